// Round 8
// baseline (190.947 us; speedup 1.0000x reference)
//
#include <hip/hip_runtime.h>
#include <hip/hip_bf16.h>

// ---------------------------------------------------------------------------
// ViLLayer forward, round 7:
//   gemm_up: BN 128->64 (2x blocks, 6 waves/SIMD) + FULL K-loop unroll
//   (60 independent loads/wave, hoistable) — the proven gemm_down recipe.
// ---------------------------------------------------------------------------

#define B_     4
#define S_     1024
#define DIM_   384
#define INNER_ 768
#define NHM_   4
#define DH_    192
#define NTOK   (B_*S_)      // 4096
#define SLOTS_ 40           // sum over t of ceil((t+1)/4)

typedef __attribute__((ext_vector_type(8))) __bf16 bf16x8v;
typedef __attribute__((ext_vector_type(4))) float  f32x4;

static __device__ __forceinline__ f32x4 mfma16(bf16x8v a, bf16x8v b, f32x4 c) {
  return __builtin_amdgcn_mfma_f32_16x16x32_bf16(a, b, c, 0, 0, 0);
}

// ---------------- cast fp32 -> bf16 (vectorized) ---------------------------
__global__ __launch_bounds__(256) void cast_bf16_k(
    const float* __restrict__ in, __hip_bfloat16* __restrict__ out, int n4)
{
  const int i = blockIdx.x * 256 + threadIdx.x;
  if (i >= n4) return;
  const float4 v = *(const float4*)&in[i * 4];
  out[i * 4 + 0] = __float2bfloat16(v.x);
  out[i * 4 + 1] = __float2bfloat16(v.y);
  out[i * 4 + 2] = __float2bfloat16(v.z);
  out[i * 4 + 3] = __float2bfloat16(v.w);
}

// ---------------- up-proj: bf16 MFMA GEMM, BN=64, full unroll --------------
// C[4096][1536] = xb[4096][384] @ Wb[1536][384]^T + b.
// grid (24, 64), 256 thr = 4 waves; wave w: rows m0+w*16..+15, cols n0..n0+63.
__global__ __launch_bounds__(256) void gemm_up_k(
    const __hip_bfloat16* __restrict__ xb, const __hip_bfloat16* __restrict__ Wb,
    const float* __restrict__ bias, float* __restrict__ C)
{
  const int n0 = blockIdx.x * 64, m0 = blockIdx.y * 64;
  const int wave = threadIdx.x >> 6, lane = threadIdx.x & 63;
  const int lrow = lane & 15, lgrp = lane >> 4;
  const __hip_bfloat16* xr = xb + (size_t)(m0 + wave * 16 + lrow) * DIM_;
  const __hip_bfloat16* wr = Wb + (size_t)(n0 + lrow) * DIM_;
  f32x4 acc[4];
  #pragma unroll
  for (int nt = 0; nt < 4; ++nt) acc[nt] = f32x4{0.f, 0.f, 0.f, 0.f};
  #pragma unroll
  for (int k0 = 0; k0 < DIM_; k0 += 32) {      // fully unrolled (12 steps)
    const bf16x8v af = *(const bf16x8v*)&xr[k0 + lgrp * 8];
    #pragma unroll
    for (int nt = 0; nt < 4; ++nt) {
      const bf16x8v bf = *(const bf16x8v*)&wr[(size_t)nt * 16 * DIM_ + k0 + lgrp * 8];
      acc[nt] = mfma16(af, bf, acc[nt]);
    }
  }
  #pragma unroll
  for (int nt = 0; nt < 4; ++nt) {
    const int n = n0 + nt * 16 + lrow;
    const float bv = bias[n];
    #pragma unroll
    for (int r = 0; r < 4; ++r) {
      const int m = m0 + wave * 16 + lgrp * 4 + r;
      C[(size_t)m * 1536 + n] = acc[nt][r] + bv;
    }
  }
}

// ---------------- down-proj: split-K bf16 MFMA partials --------------------
__global__ __launch_bounds__(256) void gemm_down_part_k(
    const __hip_bfloat16* __restrict__ hsb, const __hip_bfloat16* __restrict__ Wdb,
    float* __restrict__ pws)
{
  const int n0 = blockIdx.x * 128, m0 = blockIdx.y * 64;
  const int kbase = blockIdx.z * 192;
  const int wave = threadIdx.x >> 6, lane = threadIdx.x & 63;
  const int lrow = lane & 15, lgrp = lane >> 4;
  const __hip_bfloat16* ar = hsb + (size_t)(m0 + wave * 16 + lrow) * INNER_ + kbase;
  f32x4 acc[8];
  #pragma unroll
  for (int nt = 0; nt < 8; ++nt) acc[nt] = f32x4{0.f, 0.f, 0.f, 0.f};
  #pragma unroll
  for (int kc = 0; kc < 6; ++kc) {
    const bf16x8v af = *(const bf16x8v*)&ar[kc * 32 + lgrp * 8];
    #pragma unroll
    for (int nt = 0; nt < 8; ++nt) {
      const bf16x8v bf = *(const bf16x8v*)
          &Wdb[(size_t)(n0 + nt * 16 + lrow) * INNER_ + kbase + kc * 32 + lgrp * 8];
      acc[nt] = mfma16(af, bf, acc[nt]);
    }
  }
  float* po = pws + (size_t)blockIdx.z * NTOK * DIM_;
  #pragma unroll
  for (int nt = 0; nt < 8; ++nt) {
    const int n = n0 + nt * 16 + lrow;
    #pragma unroll
    for (int r = 0; r < 4; ++r) {
      const int m = m0 + wave * 16 + lgrp * 4 + r;
      po[(size_t)m * DIM_ + n] = acc[nt][r];
    }
  }
}

// ---------------- down-proj reduce: out = sum_z pws + bias -----------------
__global__ __launch_bounds__(256) void gemm_down_red_k(
    const float* __restrict__ pws, const float* __restrict__ bias,
    float* __restrict__ out)
{
  const int i = blockIdx.x * 256 + threadIdx.x;     // over NTOK*384/4
  if (i >= NTOK * DIM_ / 4) return;
  const int n4 = (i % (DIM_ / 4)) * 4;
  const float4 bv = *(const float4*)&bias[n4];
  float4 s0 = *(const float4*)&pws[(size_t)i * 4];
  const float4 s1 = *(const float4*)&pws[(size_t)NTOK * DIM_ * 1 + (size_t)i * 4];
  const float4 s2 = *(const float4*)&pws[(size_t)NTOK * DIM_ * 2 + (size_t)i * 4];
  const float4 s3 = *(const float4*)&pws[(size_t)NTOK * DIM_ * 3 + (size_t)i * 4];
  s0.x += s1.x + s2.x + s3.x + bv.x;
  s0.y += s1.y + s2.y + s3.y + bv.y;
  s0.z += s1.z + s2.z + s3.z + bv.z;
  s0.w += s1.w + s2.w + s3.w + bv.w;
  *(float4*)&out[(size_t)i * 4] = s0;
}

// ---------------- depthwise 3x3 conv + bias + SiLU (float4 channels) -------
__global__ __launch_bounds__(256) void conv_silu_k(
    const float* __restrict__ xi, const float* __restrict__ cw,
    const float* __restrict__ cb, float* __restrict__ ca)
{
  const int idx = blockIdx.x * 256 + threadIdx.x;     // over NTOK*192
  if (idx >= NTOK * 192) return;
  const int c4 = (idx % 192) * 4;
  const int t = idx / 192;
  const int s = t & 1023;
  const int y = s >> 5, x = s & 31;
  const int tb = t - s;
  float4 acc = *(const float4*)&cb[c4];
  #pragma unroll
  for (int ky = -1; ky <= 1; ++ky) {
    const int yy = y + ky;
    if (yy < 0 || yy > 31) continue;
    #pragma unroll
    for (int kx = -1; kx <= 1; ++kx) {
      const int xx = x + kx;
      if (xx < 0 || xx > 31) continue;
      const float4 v = *(const float4*)&xi[(size_t)(tb + (yy << 5) + xx) * 1536 + c4];
      const float4 w = *(const float4*)&cw[((ky + 1) * 3 + (kx + 1)) * INNER_ + c4];
      acc.x += v.x * w.x; acc.y += v.y * w.y;
      acc.z += v.z * w.z; acc.w += v.w * w.w;
    }
  }
  float4 o;
  o.x = acc.x / (1.f + __expf(-acc.x));
  o.y = acc.y / (1.f + __expf(-acc.y));
  o.z = acc.z / (1.f + __expf(-acc.z));
  o.w = acc.w / (1.f + __expf(-acc.w));
  *(float4*)&ca[(size_t)t * INNER_ + c4] = o;
}

// ---------------- headwise q,k,v + gate pre-activations --------------------
__global__ __launch_bounds__(256) void headwise_gates_k(
    const float* __restrict__ xi, const float* __restrict__ ca,
    const float* __restrict__ Wq, const float* __restrict__ bq,
    const float* __restrict__ Wk, const float* __restrict__ bk,
    const float* __restrict__ Wv, const float* __restrict__ bv,
    const float* __restrict__ Wig, const float* __restrict__ big,
    const float* __restrict__ Wfg, const float* __restrict__ bfg,
    __hip_bfloat16* __restrict__ qbf, __hip_bfloat16* __restrict__ kbf,
    __hip_bfloat16* __restrict__ vbf,
    float* __restrict__ ig, float* __restrict__ fg)
{
  __shared__ float qs[INNER_], ks[INNER_], vs[INNER_];
  const int t = blockIdx.x;
  const int b = t >> 10, s = t & 1023;
  const int tid = threadIdx.x;
  if (tid < 192) {
    float cav[4], xmv[4];
    #pragma unroll
    for (int d = 0; d < 4; ++d) {
      cav[d] = ca[(size_t)t * INNER_ + tid * 4 + d];
      xmv[d] = xi[(size_t)t * 1536 + tid * 4 + d];
    }
    #pragma unroll
    for (int o = 0; o < 4; ++o) {
      const int cidx = tid * 4 + o;
      float q = bq[cidx], k = bk[cidx], v = bv[cidx];
      #pragma unroll
      for (int d = 0; d < 4; ++d) {
        q += cav[d] * Wq[tid * 16 + o * 4 + d];
        k += cav[d] * Wk[tid * 16 + o * 4 + d];
        v += xmv[d] * Wv[tid * 16 + o * 4 + d];
      }
      qs[cidx] = q; ks[cidx] = k; vs[cidx] = v;
      const int hm = cidx / DH_, dd = cidx % DH_;
      const size_t o2 = ((size_t)(b * NHM_ + hm) * S_ + s) * DH_ + dd;
      qbf[o2] = __float2bfloat16(q);
      kbf[o2] = __float2bfloat16(k);
      vbf[o2] = __float2bfloat16(v);
    }
  }
  __syncthreads();
  const int g = tid >> 5, l32 = tid & 31;
  const float* Wg = (g < 4) ? Wig : Wfg;
  const int h = g & 3;
  float sum = 0.f;
  for (int c = l32; c < INNER_; c += 32) {
    sum += qs[c] * Wg[h * 2304 + c]
         + ks[c] * Wg[h * 2304 + 768 + c]
         + vs[c] * Wg[h * 2304 + 1536 + c];
  }
  #pragma unroll
  for (int m = 16; m >= 1; m >>= 1) sum += __shfl_xor(sum, m);
  if (l32 == 0) {
    if (g < 4) ig[(size_t)(b * NHM_ + h) * S_ + s] = sum + big[h];
    else       fg[(size_t)(b * NHM_ + h) * S_ + s] = sum + bfg[h];
  }
}

// ---------------- V transpose: vtb[bh][d][s] = vbf[bh][s][d] ---------------
__global__ __launch_bounds__(256) void transpose_v_k(
    const __hip_bfloat16* __restrict__ vbf, __hip_bfloat16* __restrict__ vtb)
{
  __shared__ __hip_bfloat16 tile[64][72];
  const int s0 = blockIdx.x * 64, d0 = blockIdx.y * 64, bh = blockIdx.z;
  const int tid = threadIdx.x;
  const int rr = tid >> 3;          // 0..31
  const int cc8 = (tid & 7) * 8;    // 0..56
  #pragma unroll
  for (int it = 0; it < 2; ++it) {
    const int r = rr + it * 32;
    *(bf16x8v*)&tile[r][cc8] =
        *(const bf16x8v*)&vbf[((size_t)bh * S_ + s0 + r) * DH_ + d0 + cc8];
  }
  __syncthreads();
  #pragma unroll
  for (int it = 0; it < 2; ++it) {
    const int r = rr + it * 32;     // d_local
    bf16x8v tmp;
    #pragma unroll
    for (int e = 0; e < 8; ++e) tmp[e] = *(__bf16*)&tile[cc8 + e][r];
    *(bf16x8v*)&vtb[((size_t)bh * DH_ + d0 + r) * S_ + s0 + cc8] = tmp;
  }
}

// ---------------- per-(b,h) scans ------------------------------------------
__global__ __launch_bounds__(64) void gate_scan_k(
    const float* __restrict__ ig, const float* __restrict__ fg,
    float* __restrict__ lfc, float* __restrict__ aa, float* __restrict__ rm)
{
  const int bh = blockIdx.x;
  const int lane = threadIdx.x;
  const float* fgp = fg + bh * S_;
  const float* igp = ig + bh * S_;
  float v[16];
  float run = 0.f;
  #pragma unroll
  for (int i = 0; i < 16; ++i) {
    const float x = fgp[lane * 16 + i];
    const float lf = fminf(x, 0.f) - log1pf(expf(-fabsf(x)));
    run += lf;
    v[i] = run;
  }
  float inc = run;
  #pragma unroll
  for (int off = 1; off < 64; off <<= 1) {
    const float o = __shfl_up(inc, off);
    if (lane >= off) inc += o;
  }
  const float excl = inc - run;
  float rv[16];
  float rmx = -INFINITY;
  #pragma unroll
  for (int i = 0; i < 16; ++i) {
    const float l = v[i] + excl;
    lfc[bh * S_ + lane * 16 + i] = l;
    const float a = igp[lane * 16 + i] - l;
    aa[bh * S_ + lane * 16 + i] = a;
    rmx = fmaxf(rmx, a);
    rv[i] = rmx;
  }
  float incm = rmx;
  #pragma unroll
  for (int off = 1; off < 64; off <<= 1) {
    const float o = __shfl_up(incm, off);
    if (lane >= off) incm = fmaxf(incm, o);
  }
  float exm = __shfl_up(incm, 1);
  if (lane == 0) exm = -INFINITY;
  #pragma unroll
  for (int i = 0; i < 16; ++i) {
    rm[bh * S_ + lane * 16 + i] = fmaxf(rv[i], exm);
  }
}

// ---------------- mLSTM attention: partial kernel --------------------------
__global__ __launch_bounds__(256) void mlstm_part_k(
    const __hip_bfloat16* __restrict__ qbf, const __hip_bfloat16* __restrict__ kbf,
    const __hip_bfloat16* __restrict__ vtb,
    const float* __restrict__ aa, const float* __restrict__ rm,
    float* __restrict__ pacc, float* __restrict__ rsp)
{
  __shared__ __hip_bfloat16 Kl[2][6144];
  __shared__ __hip_bfloat16 Vl[2][6144];
  __shared__ __hip_bfloat16 Pl[4][16][40];
  const int bh = blockIdx.y;
  const int slot = blockIdx.x;
  int t = 0, base = 0;
  #pragma unroll
  for (int s = 0; s < 16; ++s) {
    const int sz = (s >> 2) + 1;
    if (slot >= base + sz) { base += sz; t = s + 1; }
  }
  const int c = slot - base;
  const int jt_lo = c * 8;
  const int jt_hi = min(jt_lo + 8, 2 * t + 2);

  const int wave = threadIdx.x >> 6, lane = threadIdx.x & 63;
  const int lrow = lane & 15, lgrp = lane >> 4;
  const int q0 = t * 64 + wave * 16;
  const __hip_bfloat16* Q  = qbf + (size_t)bh * S_ * DH_;
  const __hip_bfloat16* Kp = kbf + (size_t)bh * S_ * DH_;
  const __hip_bfloat16* VT = vtb + (size_t)bh * DH_ * S_;
  const float* aap = aa + bh * S_;
  const float* rmp = rm + bh * S_;

  bf16x8v qf[6];
  #pragma unroll
  for (int kk = 0; kk < 6; ++kk)
    qf[kk] = *(const bf16x8v*)&Q[(size_t)(q0 + lrow) * DH_ + kk * 32 + lgrp * 8];
  float rmi[4];
  #pragma unroll
  for (int r = 0; r < 4; ++r) rmi[r] = rmp[q0 + lgrp * 4 + r];

  const f32x4 zero4 = {0.f, 0.f, 0.f, 0.f};
  f32x4 hacc[12];
  #pragma unroll
  for (int dd = 0; dd < 12; ++dd) hacc[dd] = zero4;
  float rs[4] = {0.f, 0.f, 0.f, 0.f};
  const float scale = 0.07216878364870323f;   // 1/sqrt(192)
  const int myqmax = q0 + 15;

  bf16x8v kreg[3], vreg[3];
  const int s0_ = wave * 192 + lane;

  auto stage_load = [&](int j0s) {
    #pragma unroll
    for (int i = 0; i < 3; ++i) {
      const int s = s0_ + i * 64;
      const int kk = s >> 7, jr = (s >> 2) & 31, g = s & 3;
      kreg[i] = *(const bf16x8v*)&Kp[(size_t)(j0s + jr) * DH_ + kk * 32 + g * 8];
      const int d = s >> 2;
      vreg[i] = *(const bf16x8v*)&VT[(size_t)d * S_ + j0s + g * 8];
    }
  };
  auto stage_write = [&](int buf) {
    #pragma unroll
    for (int i = 0; i < 3; ++i) {
      const int s = s0_ + i * 64;
      *(bf16x8v*)&Kl[buf][s << 3] = kreg[i];
      *(bf16x8v*)&Vl[buf][s << 3] = vreg[i];
    }
  };

  stage_load(jt_lo * 32);
  stage_write(0);
  __syncthreads();
  int cur = 0;

  for (int jt = jt_lo; jt < jt_hi; ++jt) {
    const int j0 = jt * 32;
    const bool nxt = (jt + 1 < jt_hi);
    if (nxt) stage_load((jt + 1) * 32);
    if (j0 <= myqmax) {
      f32x4 sacc[2];
      sacc[0] = zero4; sacc[1] = zero4;
      #pragma unroll
      for (int jj = 0; jj < 2; ++jj) {
        #pragma unroll
        for (int kk = 0; kk < 6; ++kk) {
          const bf16x8v kf = *(const bf16x8v*)
              &Kl[cur][(kk * 128 + (jj * 16 + lrow) * 4 + lgrp) << 3];
          sacc[jj] = mfma16(qf[kk], kf, sacc[jj]);
        }
      }
      #pragma unroll
      for (int jj = 0; jj < 2; ++jj) {
        const int j = j0 + jj * 16 + lrow;
        const float ajv = aap[j];
        #pragma unroll
        for (int r = 0; r < 4; ++r) {
          const int i_ = q0 + lgrp * 4 + r;
          float cval = 0.f;
          if (j <= i_) cval = sacc[jj][r] * scale * __expf(ajv - rmi[r]);
          rs[r] += cval;
          Pl[wave][lgrp * 4 + r][jj * 16 + lrow] = __float2bfloat16(cval);
        }
      }
      const bf16x8v pf = *(const bf16x8v*)&Pl[wave][lrow][lgrp * 8];
      #pragma unroll
      for (int dd = 0; dd < 12; ++dd) {
        const bf16x8v vf = *(const bf16x8v*)
            &Vl[cur][(dd * 64 + lrow * 4 + lgrp) << 3];
        hacc[dd] = mfma16(pf, vf, hacc[dd]);
      }
    }
    if (nxt) stage_write(cur ^ 1);
    __syncthreads();
    cur ^= 1;
  }

  #pragma unroll
  for (int r = 0; r < 4; ++r) {
    #pragma unroll
    for (int m = 1; m < 16; m <<= 1) rs[r] += __shfl_xor(rs[r], m);
  }
  const size_t pb16 = ((size_t)bh * SLOTS_ + slot) * 16 + wave * 4 + lgrp;
  #pragma unroll
  for (int dd = 0; dd < 12; ++dd) {
    *(f32x4*)&pacc[(pb16 * 12 + dd) * 64 + lrow * 4] = hacc[dd];
  }
  if (lrow == 0) {
    #pragma unroll
    for (int r = 0; r < 4; ++r)
      rsp[((size_t)bh * SLOTS_ + slot) * 64 + wave * 16 + lgrp * 4 + r] = rs[r];
  }
}

// ---------------- mLSTM reduce + fused epilogue (bf16 h_state out) ---------
__global__ __launch_bounds__(256) void mlstm_red_k(
    const float* __restrict__ pacc, const float* __restrict__ rsp,
    const float* __restrict__ lfc, const float* __restrict__ rm,
    const float* __restrict__ ca, const float* __restrict__ xi,
    const float* __restrict__ nw, const float* __restrict__ nb,
    const float* __restrict__ skip, __hip_bfloat16* __restrict__ hs)
{
  const int t = blockIdx.x, bh = blockIdx.y;
  const int b = bh >> 2, hm = bh & 3;
  int base = 0;
  #pragma unroll
  for (int s = 0; s < 16; ++s) if (s < t) base += (s >> 2) + 1;
  const int nc = (t >> 2) + 1;

  const int wave = threadIdx.x >> 6, lane = threadIdx.x & 63;
  const int lrow = lane & 15, lgrp = lane >> 4;
  const int q0 = t * 64 + wave * 16;
  const float* lfcp = lfc + bh * S_;
  const float* rmp  = rm + bh * S_;

  f32x4 hsum[12];
  #pragma unroll
  for (int dd = 0; dd < 12; ++dd) hsum[dd] = f32x4{0.f, 0.f, 0.f, 0.f};
  float rst[4] = {0.f, 0.f, 0.f, 0.f};

  for (int cc = 0; cc < nc; ++cc) {
    const size_t pb16 = ((size_t)bh * SLOTS_ + base + cc) * 16 + wave * 4 + lgrp;
    #pragma unroll
    for (int dd = 0; dd < 12; ++dd) {
      const f32x4 p = *(const f32x4*)&pacc[(pb16 * 12 + dd) * 64 + lrow * 4];
      hsum[dd] += p;
    }
    #pragma unroll
    for (int r = 0; r < 4; ++r)
      rst[r] += rsp[((size_t)bh * SLOTS_ + base + cc) * 64 + wave * 16 + lgrp * 4 + r];
  }

  #pragma unroll
  for (int r = 0; r < 4; ++r) {
    const int i_ = q0 + lgrp * 4 + r;
    const int tok = b * S_ + i_;
    const float mld = lfcp[i_] + rmp[i_];
    const float nrm = fmaxf(fabsf(rst[r]), __expf(-mld)) + 1e-6f;
    float hv[12];
    float sum = 0.f, sq = 0.f;
    #pragma unroll
    for (int dd = 0; dd < 12; ++dd) {
      const float x = hsum[dd][r] / nrm;
      hv[dd] = x; sum += x; sq += x * x;
    }
    #pragma unroll
    for (int m = 1; m < 16; m <<= 1) {
      sum += __shfl_xor(sum, m);
      sq  += __shfl_xor(sq, m);
    }
    const float mean = sum * (1.f / 192.f);
    const float var  = sq * (1.f / 192.f) - mean * mean;
    const float rstd = rsqrtf(var + 1e-5f);
    #pragma unroll
    for (int dd = 0; dd < 12; ++dd) {
      const int cidx = hm * DH_ + dd * 16 + lrow;
      const float hn = (hv[dd] - mean) * rstd * nw[cidx] + nb[cidx];
      const float cav = ca[(size_t)tok * INNER_ + cidx];
      const float zz  = xi[(size_t)tok * 1536 + 768 + cidx];
      const float hsv = (hn + skip[cidx] * cav) * (zz / (1.f + __expf(-zz)));
      hs[(size_t)tok * INNER_ + cidx] = __float2bfloat16(hsv);
    }
  }
}

// ---------------------------------------------------------------------------
extern "C" void kernel_launch(void* const* d_in, const int* in_sizes, int n_in,
                              void* d_out, int out_size, void* d_ws, size_t ws_size,
                              hipStream_t stream) {
  const float* x      = (const float*)d_in[0];
  const float* W_up   = (const float*)d_in[1];
  const float* b_up   = (const float*)d_in[2];
  const float* Wq     = (const float*)d_in[3];
  const float* bq     = (const float*)d_in[4];
  const float* Wk     = (const float*)d_in[5];
  const float* bk     = (const float*)d_in[6];
  const float* Wv     = (const float*)d_in[7];
  const float* bv     = (const float*)d_in[8];
  const float* conv_w = (const float*)d_in[9];
  const float* conv_b = (const float*)d_in[10];
  const float* W_ig   = (const float*)d_in[11];
  const float* b_ig   = (const float*)d_in[12];
  const float* W_fg   = (const float*)d_in[13];
  const float* b_fg   = (const float*)d_in[14];
  const float* norm_w = (const float*)d_in[15];
  const float* norm_b = (const float*)d_in[16];
  const float* skip   = (const float*)d_in[17];
  const float* W_down = (const float*)d_in[18];
  const float* b_down = (const float*)d_in[19];
  float* out = (float*)d_out;

  char* ws = (char*)d_ws;
  constexpr size_t OFF_XI  = 0;
  constexpr size_t OFF_CA  = OFF_XI + (size_t)NTOK * 1536 * 4;
  constexpr size_t OFF_QBF = OFF_CA + (size_t)NTOK * INNER_ * 4;
  constexpr size_t OFF_KBF = OFF_QBF + (size_t)16 * S_ * DH_ * 2;
  constexpr size_t OFF_VBF = OFF_KBF + (size_t)16 * S_ * DH_ * 2;
  constexpr size_t OFF_IG  = OFF_VBF + (size_t)16 * S_ * DH_ * 2;
  constexpr size_t OFF_FG  = OFF_IG + (size_t)16 * S_ * 4;
  constexpr size_t OFF_LFC = OFF_FG + (size_t)16 * S_ * 4;
  constexpr size_t OFF_AA  = OFF_LFC + (size_t)16 * S_ * 4;
  constexpr size_t OFF_RM  = OFF_AA + (size_t)16 * S_ * 4;
  constexpr size_t OFF_HS  = OFF_RM + (size_t)16 * S_ * 4;
  constexpr size_t OFF_XB  = OFF_HS + (size_t)NTOK * INNER_ * 4;
  constexpr size_t OFF_WUB = OFF_XB + (size_t)NTOK * DIM_ * 2;
  constexpr size_t OFF_PAC = OFF_WUB + (size_t)1536 * DIM_ * 2;
  constexpr size_t OFF_RSP = OFF_PAC + (size_t)16 * SLOTS_ * 64 * 192 * 4;
  constexpr size_t OFF_WDB = OFF_RSP + (size_t)16 * SLOTS_ * 64 * 4;
  constexpr size_t OFF_VTB = OFF_WDB + (size_t)DIM_ * INNER_ * 2;

  float* x_inner = (float*)(ws + OFF_XI);
  float* conv_a  = (float*)(ws + OFF_CA);
  __hip_bfloat16* qbf = (__hip_bfloat16*)(ws + OFF_QBF);
  __hip_bfloat16* kbf = (__hip_bfloat16*)(ws + OFF_KBF);
  __hip_bfloat16* vbf = (__hip_bfloat16*)(ws + OFF_VBF);
  float* ig  = (float*)(ws + OFF_IG);
  float* fg  = (float*)(ws + OFF_FG);
  float* lfc = (float*)(ws + OFF_LFC);
  float* aav = (float*)(ws + OFF_AA);
  float* rmv = (float*)(ws + OFF_RM);
  __hip_bfloat16* hsb = (__hip_bfloat16*)(ws + OFF_HS);
  __hip_bfloat16* xb  = (__hip_bfloat16*)(ws + OFF_XB);
  __hip_bfloat16* wub = (__hip_bfloat16*)(ws + OFF_WUB);
  float* pacc = (float*)(ws + OFF_PAC);
  float* rsp  = (float*)(ws + OFF_RSP);
  __hip_bfloat16* wdb = (__hip_bfloat16*)(ws + OFF_WDB);
  __hip_bfloat16* vtb = (__hip_bfloat16*)(ws + OFF_VTB);
  float* pws = pacc;   // split-K partials alias dead pacc region (25.2 <= 31.5 MB)

  // 0) casts
  cast_bf16_k<<<(NTOK * DIM_ / 4 + 255) / 256, 256, 0, stream>>>(x, xb, NTOK * DIM_ / 4);
  cast_bf16_k<<<(1536 * DIM_ / 4 + 255) / 256, 256, 0, stream>>>(W_up, wub, 1536 * DIM_ / 4);
  cast_bf16_k<<<(DIM_ * INNER_ / 4 + 255) / 256, 256, 0, stream>>>(W_down, wdb, DIM_ * INNER_ / 4);
  // 1) up-projection (bf16 MFMA, BN=64, full unroll)
  gemm_up_k<<<dim3(24, 64), 256, 0, stream>>>(xb, wub, b_up, x_inner);
  // 2) depthwise conv + SiLU
  conv_silu_k<<<(NTOK * 192) / 256, 256, 0, stream>>>(x_inner, conv_w, conv_b, conv_a);
  // 3) headwise q,k,v + gates
  headwise_gates_k<<<NTOK, 256, 0, stream>>>(
      x_inner, conv_a, Wq, bq, Wk, bk, Wv, bv, W_ig, b_ig, W_fg, b_fg,
      qbf, kbf, vbf, ig, fg);
  // 3b) V transpose
  transpose_v_k<<<dim3(16, 3, 16), 256, 0, stream>>>(vbf, vtb);
  // 4) gate scans
  gate_scan_k<<<16, 64, 0, stream>>>(ig, fg, lfc, aav, rmv);
  // 5a) attention partials
  mlstm_part_k<<<dim3(SLOTS_, 16), 256, 0, stream>>>(qbf, kbf, vtb, aav, rmv, pacc, rsp);
  // 5b) reduce + epilogue
  mlstm_red_k<<<dim3(16, 16), 256, 0, stream>>>(
      pacc, rsp, lfc, rmv, conv_a, x_inner, norm_w, norm_b, skip, hsb);
  // 6) down-projection: split-K partials + reduce
  gemm_down_part_k<<<dim3(3, 64, 4), 256, 0, stream>>>(hsb, wdb, pws);
  gemm_down_red_k<<<(NTOK * DIM_ / 4 + 255) / 256, 256, 0, stream>>>(pws, b_down, out);
}

// Round 9
// 151.272 us; speedup vs baseline: 1.2623x; 1.2623x over previous
//
#include <hip/hip_runtime.h>
#include <hip/hip_bf16.h>

// ---------------------------------------------------------------------------
// ViLLayer forward, round 8:
//   Both GEMMs rebuilt on the R5-proven structure: cooperative double-buffered
//   LDS staging (issue-early/ds_write-late), fragment-ordered 16B slots,
//   one barrier per BK=64 step.  gemm_lds_k<KD,BIAS> serves up-proj (384,true)
//   and down-proj split-K partials (192,false, z-grid).
// ---------------------------------------------------------------------------

#define B_     4
#define S_     1024
#define DIM_   384
#define INNER_ 768
#define NHM_   4
#define DH_    192
#define NTOK   (B_*S_)      // 4096
#define SLOTS_ 40           // sum over t of ceil((t+1)/4)

typedef __attribute__((ext_vector_type(8))) __bf16 bf16x8v;
typedef __attribute__((ext_vector_type(4))) float  f32x4;

static __device__ __forceinline__ f32x4 mfma16(bf16x8v a, bf16x8v b, f32x4 c) {
  return __builtin_amdgcn_mfma_f32_16x16x32_bf16(a, b, c, 0, 0, 0);
}

// ---------------- cast fp32 -> bf16 (vectorized) ---------------------------
__global__ __launch_bounds__(256) void cast_bf16_k(
    const float* __restrict__ in, __hip_bfloat16* __restrict__ out, int n4)
{
  const int i = blockIdx.x * 256 + threadIdx.x;
  if (i >= n4) return;
  const float4 v = *(const float4*)&in[i * 4];
  out[i * 4 + 0] = __float2bfloat16(v.x);
  out[i * 4 + 1] = __float2bfloat16(v.y);
  out[i * 4 + 2] = __float2bfloat16(v.z);
  out[i * 4 + 3] = __float2bfloat16(v.w);
}

// ---------------- LDS-staged bf16 MFMA GEMM tile ---------------------------
// C[m0+64][n0+64] (+= over z for split-K) = A[64][KD] @ B[64][KD]^T.
// A rows: m0.., lda; B rows: n0.., ldb. blockIdx.z selects K-chunk of KD and
// partial-output plane z (C += z*NTOK*ldc). BIAS adds bias[n] (only z==0 use).
// LDS slot layout (16B slots): slot = kk*256 + row*4 + g, kk = k-subtile of 32,
// g = 8-elem chunk; staging writes lane-consecutive, frag reads 64-consecutive.
template<int KD, bool BIAS>
__global__ __launch_bounds__(256) void gemm_lds_k(
    const __hip_bfloat16* __restrict__ A, int lda,
    const __hip_bfloat16* __restrict__ Bw, int ldb,
    const float* __restrict__ bias, float* __restrict__ C, int ldc)
{
  constexpr int NSTEP = KD / 64;
  __shared__ __hip_bfloat16 Al[2][4096];   // 512 slots * 8 elems = 8 KB
  __shared__ __hip_bfloat16 Bl[2][4096];
  const int n0 = blockIdx.x * 64, m0 = blockIdx.y * 64;
  const int kofs = blockIdx.z * KD;
  const int tid = threadIdx.x;
  const int wave = tid >> 6, lane = tid & 63;
  const int lrow = lane & 15, lgrp = lane >> 4;

  const __hip_bfloat16* Ap = A + kofs;
  const __hip_bfloat16* Bp = Bw + kofs;
  float* Cp = C + (size_t)blockIdx.z * NTOK * ldc;

  // staging decode for slots s = tid, tid+256
  const int r0 = tid >> 2, g0 = tid & 3;          // s=tid   -> kk=0
  bf16x8v areg[2], breg[2];
  auto sload = [&](int k0) {
    areg[0] = *(const bf16x8v*)&Ap[(size_t)(m0 + r0) * lda + k0 + g0 * 8];
    breg[0] = *(const bf16x8v*)&Bp[(size_t)(n0 + r0) * ldb + k0 + g0 * 8];
    areg[1] = *(const bf16x8v*)&Ap[(size_t)(m0 + r0) * lda + k0 + 32 + g0 * 8];
    breg[1] = *(const bf16x8v*)&Bp[(size_t)(n0 + r0) * ldb + k0 + 32 + g0 * 8];
  };
  auto swrite = [&](int buf) {
    *(bf16x8v*)&Al[buf][(size_t)tid * 8]         = areg[0];
    *(bf16x8v*)&Bl[buf][(size_t)tid * 8]         = breg[0];
    *(bf16x8v*)&Al[buf][(size_t)(tid + 256) * 8] = areg[1];
    *(bf16x8v*)&Bl[buf][(size_t)(tid + 256) * 8] = breg[1];
  };

  f32x4 acc[4];
  #pragma unroll
  for (int nt = 0; nt < 4; ++nt) acc[nt] = f32x4{0.f, 0.f, 0.f, 0.f};

  sload(0);
  swrite(0);
  __syncthreads();
  int cur = 0;

  for (int ks = 0; ks < NSTEP; ++ks) {
    const bool nxt = (ks + 1 < NSTEP);
    if (nxt) sload((ks + 1) * 64);               // issue early (T14)
    #pragma unroll
    for (int kk = 0; kk < 2; ++kk) {
      const bf16x8v af = *(const bf16x8v*)
          &Al[cur][(size_t)(kk * 256 + (wave * 16 + lrow) * 4 + lgrp) * 8];
      #pragma unroll
      for (int nt = 0; nt < 4; ++nt) {
        const bf16x8v bf = *(const bf16x8v*)
            &Bl[cur][(size_t)(kk * 256 + (nt * 16 + lrow) * 4 + lgrp) * 8];
        acc[nt] = mfma16(af, bf, acc[nt]);
      }
    }
    if (nxt) swrite(cur ^ 1);                    // write late, after compute
    __syncthreads();
    cur ^= 1;
  }

  #pragma unroll
  for (int nt = 0; nt < 4; ++nt) {
    const int n = n0 + nt * 16 + lrow;
    const float bv = BIAS ? bias[n] : 0.f;
    #pragma unroll
    for (int r = 0; r < 4; ++r) {
      const int m = m0 + wave * 16 + lgrp * 4 + r;
      Cp[(size_t)m * ldc + n] = acc[nt][r] + bv;
    }
  }
}

// ---------------- down-proj reduce: out = sum_z pws + bias -----------------
__global__ __launch_bounds__(256) void gemm_down_red_k(
    const float* __restrict__ pws, const float* __restrict__ bias,
    float* __restrict__ out)
{
  const int i = blockIdx.x * 256 + threadIdx.x;     // over NTOK*384/4
  if (i >= NTOK * DIM_ / 4) return;
  const int n4 = (i % (DIM_ / 4)) * 4;
  const float4 bv = *(const float4*)&bias[n4];
  float4 s0 = *(const float4*)&pws[(size_t)i * 4];
  const float4 s1 = *(const float4*)&pws[(size_t)NTOK * DIM_ * 1 + (size_t)i * 4];
  const float4 s2 = *(const float4*)&pws[(size_t)NTOK * DIM_ * 2 + (size_t)i * 4];
  const float4 s3 = *(const float4*)&pws[(size_t)NTOK * DIM_ * 3 + (size_t)i * 4];
  s0.x += s1.x + s2.x + s3.x + bv.x;
  s0.y += s1.y + s2.y + s3.y + bv.y;
  s0.z += s1.z + s2.z + s3.z + bv.z;
  s0.w += s1.w + s2.w + s3.w + bv.w;
  *(float4*)&out[(size_t)i * 4] = s0;
}

// ---------------- depthwise 3x3 conv + bias + SiLU (float4 channels) -------
__global__ __launch_bounds__(256) void conv_silu_k(
    const float* __restrict__ xi, const float* __restrict__ cw,
    const float* __restrict__ cb, float* __restrict__ ca)
{
  const int idx = blockIdx.x * 256 + threadIdx.x;     // over NTOK*192
  if (idx >= NTOK * 192) return;
  const int c4 = (idx % 192) * 4;
  const int t = idx / 192;
  const int s = t & 1023;
  const int y = s >> 5, x = s & 31;
  const int tb = t - s;
  float4 acc = *(const float4*)&cb[c4];
  #pragma unroll
  for (int ky = -1; ky <= 1; ++ky) {
    const int yy = y + ky;
    if (yy < 0 || yy > 31) continue;
    #pragma unroll
    for (int kx = -1; kx <= 1; ++kx) {
      const int xx = x + kx;
      if (xx < 0 || xx > 31) continue;
      const float4 v = *(const float4*)&xi[(size_t)(tb + (yy << 5) + xx) * 1536 + c4];
      const float4 w = *(const float4*)&cw[((ky + 1) * 3 + (kx + 1)) * INNER_ + c4];
      acc.x += v.x * w.x; acc.y += v.y * w.y;
      acc.z += v.z * w.z; acc.w += v.w * w.w;
    }
  }
  float4 o;
  o.x = acc.x / (1.f + __expf(-acc.x));
  o.y = acc.y / (1.f + __expf(-acc.y));
  o.z = acc.z / (1.f + __expf(-acc.z));
  o.w = acc.w / (1.f + __expf(-acc.w));
  *(float4*)&ca[(size_t)t * INNER_ + c4] = o;
}

// ---------------- headwise q,k,v + gate pre-activations --------------------
__global__ __launch_bounds__(256) void headwise_gates_k(
    const float* __restrict__ xi, const float* __restrict__ ca,
    const float* __restrict__ Wq, const float* __restrict__ bq,
    const float* __restrict__ Wk, const float* __restrict__ bk,
    const float* __restrict__ Wv, const float* __restrict__ bv,
    const float* __restrict__ Wig, const float* __restrict__ big,
    const float* __restrict__ Wfg, const float* __restrict__ bfg,
    __hip_bfloat16* __restrict__ qbf, __hip_bfloat16* __restrict__ kbf,
    __hip_bfloat16* __restrict__ vbf,
    float* __restrict__ ig, float* __restrict__ fg)
{
  __shared__ float qs[INNER_], ks[INNER_], vs[INNER_];
  const int t = blockIdx.x;
  const int b = t >> 10, s = t & 1023;
  const int tid = threadIdx.x;
  if (tid < 192) {
    float cav[4], xmv[4];
    #pragma unroll
    for (int d = 0; d < 4; ++d) {
      cav[d] = ca[(size_t)t * INNER_ + tid * 4 + d];
      xmv[d] = xi[(size_t)t * 1536 + tid * 4 + d];
    }
    #pragma unroll
    for (int o = 0; o < 4; ++o) {
      const int cidx = tid * 4 + o;
      float q = bq[cidx], k = bk[cidx], v = bv[cidx];
      #pragma unroll
      for (int d = 0; d < 4; ++d) {
        q += cav[d] * Wq[tid * 16 + o * 4 + d];
        k += cav[d] * Wk[tid * 16 + o * 4 + d];
        v += xmv[d] * Wv[tid * 16 + o * 4 + d];
      }
      qs[cidx] = q; ks[cidx] = k; vs[cidx] = v;
      const int hm = cidx / DH_, dd = cidx % DH_;
      const size_t o2 = ((size_t)(b * NHM_ + hm) * S_ + s) * DH_ + dd;
      qbf[o2] = __float2bfloat16(q);
      kbf[o2] = __float2bfloat16(k);
      vbf[o2] = __float2bfloat16(v);
    }
  }
  __syncthreads();
  const int g = tid >> 5, l32 = tid & 31;
  const float* Wg = (g < 4) ? Wig : Wfg;
  const int h = g & 3;
  float sum = 0.f;
  for (int c = l32; c < INNER_; c += 32) {
    sum += qs[c] * Wg[h * 2304 + c]
         + ks[c] * Wg[h * 2304 + 768 + c]
         + vs[c] * Wg[h * 2304 + 1536 + c];
  }
  #pragma unroll
  for (int m = 16; m >= 1; m >>= 1) sum += __shfl_xor(sum, m);
  if (l32 == 0) {
    if (g < 4) ig[(size_t)(b * NHM_ + h) * S_ + s] = sum + big[h];
    else       fg[(size_t)(b * NHM_ + h) * S_ + s] = sum + bfg[h];
  }
}

// ---------------- V transpose: vtb[bh][d][s] = vbf[bh][s][d] ---------------
__global__ __launch_bounds__(256) void transpose_v_k(
    const __hip_bfloat16* __restrict__ vbf, __hip_bfloat16* __restrict__ vtb)
{
  __shared__ __hip_bfloat16 tile[64][72];
  const int s0 = blockIdx.x * 64, d0 = blockIdx.y * 64, bh = blockIdx.z;
  const int tid = threadIdx.x;
  const int rr = tid >> 3;          // 0..31
  const int cc8 = (tid & 7) * 8;    // 0..56
  #pragma unroll
  for (int it = 0; it < 2; ++it) {
    const int r = rr + it * 32;
    *(bf16x8v*)&tile[r][cc8] =
        *(const bf16x8v*)&vbf[((size_t)bh * S_ + s0 + r) * DH_ + d0 + cc8];
  }
  __syncthreads();
  #pragma unroll
  for (int it = 0; it < 2; ++it) {
    const int r = rr + it * 32;     // d_local
    bf16x8v tmp;
    #pragma unroll
    for (int e = 0; e < 8; ++e) tmp[e] = *(__bf16*)&tile[cc8 + e][r];
    *(bf16x8v*)&vtb[((size_t)bh * DH_ + d0 + r) * S_ + s0 + cc8] = tmp;
  }
}

// ---------------- per-(b,h) scans ------------------------------------------
__global__ __launch_bounds__(64) void gate_scan_k(
    const float* __restrict__ ig, const float* __restrict__ fg,
    float* __restrict__ lfc, float* __restrict__ aa, float* __restrict__ rm)
{
  const int bh = blockIdx.x;
  const int lane = threadIdx.x;
  const float* fgp = fg + bh * S_;
  const float* igp = ig + bh * S_;
  float v[16];
  float run = 0.f;
  #pragma unroll
  for (int i = 0; i < 16; ++i) {
    const float x = fgp[lane * 16 + i];
    const float lf = fminf(x, 0.f) - log1pf(expf(-fabsf(x)));
    run += lf;
    v[i] = run;
  }
  float inc = run;
  #pragma unroll
  for (int off = 1; off < 64; off <<= 1) {
    const float o = __shfl_up(inc, off);
    if (lane >= off) inc += o;
  }
  const float excl = inc - run;
  float rv[16];
  float rmx = -INFINITY;
  #pragma unroll
  for (int i = 0; i < 16; ++i) {
    const float l = v[i] + excl;
    lfc[bh * S_ + lane * 16 + i] = l;
    const float a = igp[lane * 16 + i] - l;
    aa[bh * S_ + lane * 16 + i] = a;
    rmx = fmaxf(rmx, a);
    rv[i] = rmx;
  }
  float incm = rmx;
  #pragma unroll
  for (int off = 1; off < 64; off <<= 1) {
    const float o = __shfl_up(incm, off);
    if (lane >= off) incm = fmaxf(incm, o);
  }
  float exm = __shfl_up(incm, 1);
  if (lane == 0) exm = -INFINITY;
  #pragma unroll
  for (int i = 0; i < 16; ++i) {
    rm[bh * S_ + lane * 16 + i] = fmaxf(rv[i], exm);
  }
}

// ---------------- mLSTM attention: partial kernel --------------------------
__global__ __launch_bounds__(256) void mlstm_part_k(
    const __hip_bfloat16* __restrict__ qbf, const __hip_bfloat16* __restrict__ kbf,
    const __hip_bfloat16* __restrict__ vtb,
    const float* __restrict__ aa, const float* __restrict__ rm,
    float* __restrict__ pacc, float* __restrict__ rsp)
{
  __shared__ __hip_bfloat16 Kl[2][6144];
  __shared__ __hip_bfloat16 Vl[2][6144];
  __shared__ __hip_bfloat16 Pl[4][16][40];
  const int bh = blockIdx.y;
  const int slot = blockIdx.x;
  int t = 0, base = 0;
  #pragma unroll
  for (int s = 0; s < 16; ++s) {
    const int sz = (s >> 2) + 1;
    if (slot >= base + sz) { base += sz; t = s + 1; }
  }
  const int c = slot - base;
  const int jt_lo = c * 8;
  const int jt_hi = min(jt_lo + 8, 2 * t + 2);

  const int wave = threadIdx.x >> 6, lane = threadIdx.x & 63;
  const int lrow = lane & 15, lgrp = lane >> 4;
  const int q0 = t * 64 + wave * 16;
  const __hip_bfloat16* Q  = qbf + (size_t)bh * S_ * DH_;
  const __hip_bfloat16* Kp = kbf + (size_t)bh * S_ * DH_;
  const __hip_bfloat16* VT = vtb + (size_t)bh * DH_ * S_;
  const float* aap = aa + bh * S_;
  const float* rmp = rm + bh * S_;

  bf16x8v qf[6];
  #pragma unroll
  for (int kk = 0; kk < 6; ++kk)
    qf[kk] = *(const bf16x8v*)&Q[(size_t)(q0 + lrow) * DH_ + kk * 32 + lgrp * 8];
  float rmi[4];
  #pragma unroll
  for (int r = 0; r < 4; ++r) rmi[r] = rmp[q0 + lgrp * 4 + r];

  const f32x4 zero4 = {0.f, 0.f, 0.f, 0.f};
  f32x4 hacc[12];
  #pragma unroll
  for (int dd = 0; dd < 12; ++dd) hacc[dd] = zero4;
  float rs[4] = {0.f, 0.f, 0.f, 0.f};
  const float scale = 0.07216878364870323f;   // 1/sqrt(192)
  const int myqmax = q0 + 15;

  bf16x8v kreg[3], vreg[3];
  const int s0_ = wave * 192 + lane;

  auto stage_load = [&](int j0s) {
    #pragma unroll
    for (int i = 0; i < 3; ++i) {
      const int s = s0_ + i * 64;
      const int kk = s >> 7, jr = (s >> 2) & 31, g = s & 3;
      kreg[i] = *(const bf16x8v*)&Kp[(size_t)(j0s + jr) * DH_ + kk * 32 + g * 8];
      const int d = s >> 2;
      vreg[i] = *(const bf16x8v*)&VT[(size_t)d * S_ + j0s + g * 8];
    }
  };
  auto stage_write = [&](int buf) {
    #pragma unroll
    for (int i = 0; i < 3; ++i) {
      const int s = s0_ + i * 64;
      *(bf16x8v*)&Kl[buf][s << 3] = kreg[i];
      *(bf16x8v*)&Vl[buf][s << 3] = vreg[i];
    }
  };

  stage_load(jt_lo * 32);
  stage_write(0);
  __syncthreads();
  int cur = 0;

  for (int jt = jt_lo; jt < jt_hi; ++jt) {
    const int j0 = jt * 32;
    const bool nxt = (jt + 1 < jt_hi);
    if (nxt) stage_load((jt + 1) * 32);
    if (j0 <= myqmax) {
      f32x4 sacc[2];
      sacc[0] = zero4; sacc[1] = zero4;
      #pragma unroll
      for (int jj = 0; jj < 2; ++jj) {
        #pragma unroll
        for (int kk = 0; kk < 6; ++kk) {
          const bf16x8v kf = *(const bf16x8v*)
              &Kl[cur][(kk * 128 + (jj * 16 + lrow) * 4 + lgrp) << 3];
          sacc[jj] = mfma16(qf[kk], kf, sacc[jj]);
        }
      }
      #pragma unroll
      for (int jj = 0; jj < 2; ++jj) {
        const int j = j0 + jj * 16 + lrow;
        const float ajv = aap[j];
        #pragma unroll
        for (int r = 0; r < 4; ++r) {
          const int i_ = q0 + lgrp * 4 + r;
          float cval = 0.f;
          if (j <= i_) cval = sacc[jj][r] * scale * __expf(ajv - rmi[r]);
          rs[r] += cval;
          Pl[wave][lgrp * 4 + r][jj * 16 + lrow] = __float2bfloat16(cval);
        }
      }
      const bf16x8v pf = *(const bf16x8v*)&Pl[wave][lrow][lgrp * 8];
      #pragma unroll
      for (int dd = 0; dd < 12; ++dd) {
        const bf16x8v vf = *(const bf16x8v*)
            &Vl[cur][(dd * 64 + lrow * 4 + lgrp) << 3];
        hacc[dd] = mfma16(pf, vf, hacc[dd]);
      }
    }
    if (nxt) stage_write(cur ^ 1);
    __syncthreads();
    cur ^= 1;
  }

  #pragma unroll
  for (int r = 0; r < 4; ++r) {
    #pragma unroll
    for (int m = 1; m < 16; m <<= 1) rs[r] += __shfl_xor(rs[r], m);
  }
  const size_t pb16 = ((size_t)bh * SLOTS_ + slot) * 16 + wave * 4 + lgrp;
  #pragma unroll
  for (int dd = 0; dd < 12; ++dd) {
    *(f32x4*)&pacc[(pb16 * 12 + dd) * 64 + lrow * 4] = hacc[dd];
  }
  if (lrow == 0) {
    #pragma unroll
    for (int r = 0; r < 4; ++r)
      rsp[((size_t)bh * SLOTS_ + slot) * 64 + wave * 16 + lgrp * 4 + r] = rs[r];
  }
}

// ---------------- mLSTM reduce + fused epilogue (bf16 h_state out) ---------
__global__ __launch_bounds__(256) void mlstm_red_k(
    const float* __restrict__ pacc, const float* __restrict__ rsp,
    const float* __restrict__ lfc, const float* __restrict__ rm,
    const float* __restrict__ ca, const float* __restrict__ xi,
    const float* __restrict__ nw, const float* __restrict__ nb,
    const float* __restrict__ skip, __hip_bfloat16* __restrict__ hs)
{
  const int t = blockIdx.x, bh = blockIdx.y;
  const int b = bh >> 2, hm = bh & 3;
  int base = 0;
  #pragma unroll
  for (int s = 0; s < 16; ++s) if (s < t) base += (s >> 2) + 1;
  const int nc = (t >> 2) + 1;

  const int wave = threadIdx.x >> 6, lane = threadIdx.x & 63;
  const int lrow = lane & 15, lgrp = lane >> 4;
  const int q0 = t * 64 + wave * 16;
  const float* lfcp = lfc + bh * S_;
  const float* rmp  = rm + bh * S_;

  f32x4 hsum[12];
  #pragma unroll
  for (int dd = 0; dd < 12; ++dd) hsum[dd] = f32x4{0.f, 0.f, 0.f, 0.f};
  float rst[4] = {0.f, 0.f, 0.f, 0.f};

  for (int cc = 0; cc < nc; ++cc) {
    const size_t pb16 = ((size_t)bh * SLOTS_ + base + cc) * 16 + wave * 4 + lgrp;
    #pragma unroll
    for (int dd = 0; dd < 12; ++dd) {
      const f32x4 p = *(const f32x4*)&pacc[(pb16 * 12 + dd) * 64 + lrow * 4];
      hsum[dd] += p;
    }
    #pragma unroll
    for (int r = 0; r < 4; ++r)
      rst[r] += rsp[((size_t)bh * SLOTS_ + base + cc) * 64 + wave * 16 + lgrp * 4 + r];
  }

  #pragma unroll
  for (int r = 0; r < 4; ++r) {
    const int i_ = q0 + lgrp * 4 + r;
    const int tok = b * S_ + i_;
    const float mld = lfcp[i_] + rmp[i_];
    const float nrm = fmaxf(fabsf(rst[r]), __expf(-mld)) + 1e-6f;
    float hv[12];
    float sum = 0.f, sq = 0.f;
    #pragma unroll
    for (int dd = 0; dd < 12; ++dd) {
      const float x = hsum[dd][r] / nrm;
      hv[dd] = x; sum += x; sq += x * x;
    }
    #pragma unroll
    for (int m = 1; m < 16; m <<= 1) {
      sum += __shfl_xor(sum, m);
      sq  += __shfl_xor(sq, m);
    }
    const float mean = sum * (1.f / 192.f);
    const float var  = sq * (1.f / 192.f) - mean * mean;
    const float rstd = rsqrtf(var + 1e-5f);
    #pragma unroll
    for (int dd = 0; dd < 12; ++dd) {
      const int cidx = hm * DH_ + dd * 16 + lrow;
      const float hn = (hv[dd] - mean) * rstd * nw[cidx] + nb[cidx];
      const float cav = ca[(size_t)tok * INNER_ + cidx];
      const float zz  = xi[(size_t)tok * 1536 + 768 + cidx];
      const float hsv = (hn + skip[cidx] * cav) * (zz / (1.f + __expf(-zz)));
      hs[(size_t)tok * INNER_ + cidx] = __float2bfloat16(hsv);
    }
  }
}

// ---------------------------------------------------------------------------
extern "C" void kernel_launch(void* const* d_in, const int* in_sizes, int n_in,
                              void* d_out, int out_size, void* d_ws, size_t ws_size,
                              hipStream_t stream) {
  const float* x      = (const float*)d_in[0];
  const float* W_up   = (const float*)d_in[1];
  const float* b_up   = (const float*)d_in[2];
  const float* Wq     = (const float*)d_in[3];
  const float* bq     = (const float*)d_in[4];
  const float* Wk     = (const float*)d_in[5];
  const float* bk     = (const float*)d_in[6];
  const float* Wv     = (const float*)d_in[7];
  const float* bv     = (const float*)d_in[8];
  const float* conv_w = (const float*)d_in[9];
  const float* conv_b = (const float*)d_in[10];
  const float* W_ig   = (const float*)d_in[11];
  const float* b_ig   = (const float*)d_in[12];
  const float* W_fg   = (const float*)d_in[13];
  const float* b_fg   = (const float*)d_in[14];
  const float* norm_w = (const float*)d_in[15];
  const float* norm_b = (const float*)d_in[16];
  const float* skip   = (const float*)d_in[17];
  const float* W_down = (const float*)d_in[18];
  const float* b_down = (const float*)d_in[19];
  float* out = (float*)d_out;

  char* ws = (char*)d_ws;
  constexpr size_t OFF_XI  = 0;
  constexpr size_t OFF_CA  = OFF_XI + (size_t)NTOK * 1536 * 4;
  constexpr size_t OFF_QBF = OFF_CA + (size_t)NTOK * INNER_ * 4;
  constexpr size_t OFF_KBF = OFF_QBF + (size_t)16 * S_ * DH_ * 2;
  constexpr size_t OFF_VBF = OFF_KBF + (size_t)16 * S_ * DH_ * 2;
  constexpr size_t OFF_IG  = OFF_VBF + (size_t)16 * S_ * DH_ * 2;
  constexpr size_t OFF_FG  = OFF_IG + (size_t)16 * S_ * 4;
  constexpr size_t OFF_LFC = OFF_FG + (size_t)16 * S_ * 4;
  constexpr size_t OFF_AA  = OFF_LFC + (size_t)16 * S_ * 4;
  constexpr size_t OFF_RM  = OFF_AA + (size_t)16 * S_ * 4;
  constexpr size_t OFF_HS  = OFF_RM + (size_t)16 * S_ * 4;
  constexpr size_t OFF_XB  = OFF_HS + (size_t)NTOK * INNER_ * 4;
  constexpr size_t OFF_WUB = OFF_XB + (size_t)NTOK * DIM_ * 2;
  constexpr size_t OFF_PAC = OFF_WUB + (size_t)1536 * DIM_ * 2;
  constexpr size_t OFF_RSP = OFF_PAC + (size_t)16 * SLOTS_ * 64 * 192 * 4;
  constexpr size_t OFF_WDB = OFF_RSP + (size_t)16 * SLOTS_ * 64 * 4;
  constexpr size_t OFF_VTB = OFF_WDB + (size_t)DIM_ * INNER_ * 2;

  float* x_inner = (float*)(ws + OFF_XI);
  float* conv_a  = (float*)(ws + OFF_CA);
  __hip_bfloat16* qbf = (__hip_bfloat16*)(ws + OFF_QBF);
  __hip_bfloat16* kbf = (__hip_bfloat16*)(ws + OFF_KBF);
  __hip_bfloat16* vbf = (__hip_bfloat16*)(ws + OFF_VBF);
  float* ig  = (float*)(ws + OFF_IG);
  float* fg  = (float*)(ws + OFF_FG);
  float* lfc = (float*)(ws + OFF_LFC);
  float* aav = (float*)(ws + OFF_AA);
  float* rmv = (float*)(ws + OFF_RM);
  __hip_bfloat16* hsb = (__hip_bfloat16*)(ws + OFF_HS);
  __hip_bfloat16* xb  = (__hip_bfloat16*)(ws + OFF_XB);
  __hip_bfloat16* wub = (__hip_bfloat16*)(ws + OFF_WUB);
  float* pacc = (float*)(ws + OFF_PAC);
  float* rsp  = (float*)(ws + OFF_RSP);
  __hip_bfloat16* wdb = (__hip_bfloat16*)(ws + OFF_WDB);
  __hip_bfloat16* vtb = (__hip_bfloat16*)(ws + OFF_VTB);
  float* pws = pacc;   // split-K partials alias dead pacc region (25.2 <= 31.5 MB)

  // 0) casts
  cast_bf16_k<<<(NTOK * DIM_ / 4 + 255) / 256, 256, 0, stream>>>(x, xb, NTOK * DIM_ / 4);
  cast_bf16_k<<<(1536 * DIM_ / 4 + 255) / 256, 256, 0, stream>>>(W_up, wub, 1536 * DIM_ / 4);
  cast_bf16_k<<<(DIM_ * INNER_ / 4 + 255) / 256, 256, 0, stream>>>(W_down, wdb, DIM_ * INNER_ / 4);
  // 1) up-projection (LDS-staged bf16 MFMA, KD=384, bias)
  gemm_lds_k<DIM_, true><<<dim3(24, 64, 1), 256, 0, stream>>>(
      xb, DIM_, wub, DIM_, b_up, x_inner, 1536);
  // 2) depthwise conv + SiLU
  conv_silu_k<<<(NTOK * 192) / 256, 256, 0, stream>>>(x_inner, conv_w, conv_b, conv_a);
  // 3) headwise q,k,v + gates
  headwise_gates_k<<<NTOK, 256, 0, stream>>>(
      x_inner, conv_a, Wq, bq, Wk, bk, Wv, bv, W_ig, b_ig, W_fg, b_fg,
      qbf, kbf, vbf, ig, fg);
  // 3b) V transpose
  transpose_v_k<<<dim3(16, 3, 16), 256, 0, stream>>>(vbf, vtb);
  // 4) gate scans
  gate_scan_k<<<16, 64, 0, stream>>>(ig, fg, lfc, aav, rmv);
  // 5a) attention partials
  mlstm_part_k<<<dim3(SLOTS_, 16), 256, 0, stream>>>(qbf, kbf, vtb, aav, rmv, pacc, rsp);
  // 5b) reduce + epilogue
  mlstm_red_k<<<dim3(16, 16), 256, 0, stream>>>(
      pacc, rsp, lfc, rmv, conv_a, x_inner, norm_w, norm_b, skip, hsb);
  // 6) down-projection: LDS-staged split-K partials (KD=192, z=4) + reduce
  gemm_lds_k<192, false><<<dim3(6, 64, 4), 256, 0, stream>>>(
      hsb, INNER_, wdb, INNER_, nullptr, pws, DIM_);
  gemm_down_red_k<<<(NTOK * DIM_ / 4 + 255) / 256, 256, 0, stream>>>(pws, b_down, out);
}

// Round 10
// 139.812 us; speedup vs baseline: 1.3657x; 1.0820x over previous
//
#include <hip/hip_runtime.h>
#include <hip/hip_bf16.h>

// ---------------------------------------------------------------------------
// ViLLayer forward, round 9:
//   headwise_gates_k phase-2 gate GEMV vectorized to float4 (was 24-iter
//   scalar loop = 72 scalar global loads/lane); q/k/v bf16 stores packed
//   as single uint2 (8B) stores. Everything else unchanged from R8.
// ---------------------------------------------------------------------------

#define B_     4
#define S_     1024
#define DIM_   384
#define INNER_ 768
#define NHM_   4
#define DH_    192
#define NTOK   (B_*S_)      // 4096
#define SLOTS_ 40           // sum over t of ceil((t+1)/4)

typedef __attribute__((ext_vector_type(8))) __bf16 bf16x8v;
typedef __attribute__((ext_vector_type(4))) float  f32x4;

static __device__ __forceinline__ f32x4 mfma16(bf16x8v a, bf16x8v b, f32x4 c) {
  return __builtin_amdgcn_mfma_f32_16x16x32_bf16(a, b, c, 0, 0, 0);
}

// ---------------- cast fp32 -> bf16 (vectorized) ---------------------------
__global__ __launch_bounds__(256) void cast_bf16_k(
    const float* __restrict__ in, __hip_bfloat16* __restrict__ out, int n4)
{
  const int i = blockIdx.x * 256 + threadIdx.x;
  if (i >= n4) return;
  const float4 v = *(const float4*)&in[i * 4];
  out[i * 4 + 0] = __float2bfloat16(v.x);
  out[i * 4 + 1] = __float2bfloat16(v.y);
  out[i * 4 + 2] = __float2bfloat16(v.z);
  out[i * 4 + 3] = __float2bfloat16(v.w);
}

// ---------------- LDS-staged bf16 MFMA GEMM tile ---------------------------
template<int KD, bool BIAS>
__global__ __launch_bounds__(256) void gemm_lds_k(
    const __hip_bfloat16* __restrict__ A, int lda,
    const __hip_bfloat16* __restrict__ Bw, int ldb,
    const float* __restrict__ bias, float* __restrict__ C, int ldc)
{
  constexpr int NSTEP = KD / 64;
  __shared__ __hip_bfloat16 Al[2][4096];
  __shared__ __hip_bfloat16 Bl[2][4096];
  const int n0 = blockIdx.x * 64, m0 = blockIdx.y * 64;
  const int kofs = blockIdx.z * KD;
  const int tid = threadIdx.x;
  const int wave = tid >> 6, lane = tid & 63;
  const int lrow = lane & 15, lgrp = lane >> 4;

  const __hip_bfloat16* Ap = A + kofs;
  const __hip_bfloat16* Bp = Bw + kofs;
  float* Cp = C + (size_t)blockIdx.z * NTOK * ldc;

  const int r0 = tid >> 2, g0 = tid & 3;
  bf16x8v areg[2], breg[2];
  auto sload = [&](int k0) {
    areg[0] = *(const bf16x8v*)&Ap[(size_t)(m0 + r0) * lda + k0 + g0 * 8];
    breg[0] = *(const bf16x8v*)&Bp[(size_t)(n0 + r0) * ldb + k0 + g0 * 8];
    areg[1] = *(const bf16x8v*)&Ap[(size_t)(m0 + r0) * lda + k0 + 32 + g0 * 8];
    breg[1] = *(const bf16x8v*)&Bp[(size_t)(n0 + r0) * ldb + k0 + 32 + g0 * 8];
  };
  auto swrite = [&](int buf) {
    *(bf16x8v*)&Al[buf][(size_t)tid * 8]         = areg[0];
    *(bf16x8v*)&Bl[buf][(size_t)tid * 8]         = breg[0];
    *(bf16x8v*)&Al[buf][(size_t)(tid + 256) * 8] = areg[1];
    *(bf16x8v*)&Bl[buf][(size_t)(tid + 256) * 8] = breg[1];
  };

  f32x4 acc[4];
  #pragma unroll
  for (int nt = 0; nt < 4; ++nt) acc[nt] = f32x4{0.f, 0.f, 0.f, 0.f};

  sload(0);
  swrite(0);
  __syncthreads();
  int cur = 0;

  for (int ks = 0; ks < NSTEP; ++ks) {
    const bool nxt = (ks + 1 < NSTEP);
    if (nxt) sload((ks + 1) * 64);
    #pragma unroll
    for (int kk = 0; kk < 2; ++kk) {
      const bf16x8v af = *(const bf16x8v*)
          &Al[cur][(size_t)(kk * 256 + (wave * 16 + lrow) * 4 + lgrp) * 8];
      #pragma unroll
      for (int nt = 0; nt < 4; ++nt) {
        const bf16x8v bf = *(const bf16x8v*)
            &Bl[cur][(size_t)(kk * 256 + (nt * 16 + lrow) * 4 + lgrp) * 8];
        acc[nt] = mfma16(af, bf, acc[nt]);
      }
    }
    if (nxt) swrite(cur ^ 1);
    __syncthreads();
    cur ^= 1;
  }

  #pragma unroll
  for (int nt = 0; nt < 4; ++nt) {
    const int n = n0 + nt * 16 + lrow;
    const float bv = BIAS ? bias[n] : 0.f;
    #pragma unroll
    for (int r = 0; r < 4; ++r) {
      const int m = m0 + wave * 16 + lgrp * 4 + r;
      Cp[(size_t)m * ldc + n] = acc[nt][r] + bv;
    }
  }
}

// ---------------- down-proj reduce: out = sum_z pws + bias -----------------
__global__ __launch_bounds__(256) void gemm_down_red_k(
    const float* __restrict__ pws, const float* __restrict__ bias,
    float* __restrict__ out)
{
  const int i = blockIdx.x * 256 + threadIdx.x;
  if (i >= NTOK * DIM_ / 4) return;
  const int n4 = (i % (DIM_ / 4)) * 4;
  const float4 bv = *(const float4*)&bias[n4];
  float4 s0 = *(const float4*)&pws[(size_t)i * 4];
  const float4 s1 = *(const float4*)&pws[(size_t)NTOK * DIM_ * 1 + (size_t)i * 4];
  const float4 s2 = *(const float4*)&pws[(size_t)NTOK * DIM_ * 2 + (size_t)i * 4];
  const float4 s3 = *(const float4*)&pws[(size_t)NTOK * DIM_ * 3 + (size_t)i * 4];
  s0.x += s1.x + s2.x + s3.x + bv.x;
  s0.y += s1.y + s2.y + s3.y + bv.y;
  s0.z += s1.z + s2.z + s3.z + bv.z;
  s0.w += s1.w + s2.w + s3.w + bv.w;
  *(float4*)&out[(size_t)i * 4] = s0;
}

// ---------------- depthwise 3x3 conv + bias + SiLU (float4 channels) -------
__global__ __launch_bounds__(256) void conv_silu_k(
    const float* __restrict__ xi, const float* __restrict__ cw,
    const float* __restrict__ cb, float* __restrict__ ca)
{
  const int idx = blockIdx.x * 256 + threadIdx.x;
  if (idx >= NTOK * 192) return;
  const int c4 = (idx % 192) * 4;
  const int t = idx / 192;
  const int s = t & 1023;
  const int y = s >> 5, x = s & 31;
  const int tb = t - s;
  float4 acc = *(const float4*)&cb[c4];
  #pragma unroll
  for (int ky = -1; ky <= 1; ++ky) {
    const int yy = y + ky;
    if (yy < 0 || yy > 31) continue;
    #pragma unroll
    for (int kx = -1; kx <= 1; ++kx) {
      const int xx = x + kx;
      if (xx < 0 || xx > 31) continue;
      const float4 v = *(const float4*)&xi[(size_t)(tb + (yy << 5) + xx) * 1536 + c4];
      const float4 w = *(const float4*)&cw[((ky + 1) * 3 + (kx + 1)) * INNER_ + c4];
      acc.x += v.x * w.x; acc.y += v.y * w.y;
      acc.z += v.z * w.z; acc.w += v.w * w.w;
    }
  }
  float4 o;
  o.x = acc.x / (1.f + __expf(-acc.x));
  o.y = acc.y / (1.f + __expf(-acc.y));
  o.z = acc.z / (1.f + __expf(-acc.z));
  o.w = acc.w / (1.f + __expf(-acc.w));
  *(float4*)&ca[(size_t)t * INNER_ + c4] = o;
}

// ---------------- headwise q,k,v + gate pre-activations --------------------
__global__ __launch_bounds__(256) void headwise_gates_k(
    const float* __restrict__ xi, const float* __restrict__ ca,
    const float* __restrict__ Wq, const float* __restrict__ bq,
    const float* __restrict__ Wk, const float* __restrict__ bk,
    const float* __restrict__ Wv, const float* __restrict__ bv,
    const float* __restrict__ Wig, const float* __restrict__ big,
    const float* __restrict__ Wfg, const float* __restrict__ bfg,
    __hip_bfloat16* __restrict__ qbf, __hip_bfloat16* __restrict__ kbf,
    __hip_bfloat16* __restrict__ vbf,
    float* __restrict__ ig, float* __restrict__ fg)
{
  __shared__ float qs[INNER_], ks[INNER_], vs[INNER_];
  const int t = blockIdx.x;
  const int b = t >> 10, s = t & 1023;
  const int tid = threadIdx.x;
  if (tid < 192) {
    float cav[4], xmv[4];
    #pragma unroll
    for (int d = 0; d < 4; ++d) {
      cav[d] = ca[(size_t)t * INNER_ + tid * 4 + d];
      xmv[d] = xi[(size_t)t * 1536 + tid * 4 + d];
    }
    __hip_bfloat16 tq[4], tk[4], tv[4];
    #pragma unroll
    for (int o = 0; o < 4; ++o) {
      const int cidx = tid * 4 + o;
      float q = bq[cidx], k = bk[cidx], v = bv[cidx];
      #pragma unroll
      for (int d = 0; d < 4; ++d) {
        q += cav[d] * Wq[tid * 16 + o * 4 + d];
        k += cav[d] * Wk[tid * 16 + o * 4 + d];
        v += xmv[d] * Wv[tid * 16 + o * 4 + d];
      }
      qs[cidx] = q; ks[cidx] = k; vs[cidx] = v;
      tq[o] = __float2bfloat16(q);
      tk[o] = __float2bfloat16(k);
      tv[o] = __float2bfloat16(v);
    }
    // packed 8B stores: the 4 outputs are consecutive dd within one head
    const int cidx0 = tid * 4;
    const int hm = cidx0 / DH_, dd = cidx0 % DH_;
    const size_t o2 = ((size_t)(b * NHM_ + hm) * S_ + s) * DH_ + dd;
    *(uint2*)&qbf[o2] = *(uint2*)tq;
    *(uint2*)&kbf[o2] = *(uint2*)tk;
    *(uint2*)&vbf[o2] = *(uint2*)tv;
  }
  __syncthreads();
  // 8 groups of 32 lanes; float4-vectorized gate dot products
  const int g = tid >> 5, l32 = tid & 31;
  const float* Wg = (g < 4) ? Wig : Wfg;
  const int h = g & 3;
  float sum = 0.f;
  #pragma unroll
  for (int i = 0; i < 6; ++i) {
    const int c4 = (l32 + i * 32) * 4;
    const float4 qv = *(const float4*)&qs[c4];
    const float4 kv = *(const float4*)&ks[c4];
    const float4 vv = *(const float4*)&vs[c4];
    const float4 wq = *(const float4*)&Wg[h * 2304 + c4];
    const float4 wk = *(const float4*)&Wg[h * 2304 + 768 + c4];
    const float4 wv = *(const float4*)&Wg[h * 2304 + 1536 + c4];
    sum += qv.x * wq.x + qv.y * wq.y + qv.z * wq.z + qv.w * wq.w;
    sum += kv.x * wk.x + kv.y * wk.y + kv.z * wk.z + kv.w * wk.w;
    sum += vv.x * wv.x + vv.y * wv.y + vv.z * wv.z + vv.w * wv.w;
  }
  #pragma unroll
  for (int m = 16; m >= 1; m >>= 1) sum += __shfl_xor(sum, m);
  if (l32 == 0) {
    if (g < 4) ig[(size_t)(b * NHM_ + h) * S_ + s] = sum + big[h];
    else       fg[(size_t)(b * NHM_ + h) * S_ + s] = sum + bfg[h];
  }
}

// ---------------- V transpose: vtb[bh][d][s] = vbf[bh][s][d] ---------------
__global__ __launch_bounds__(256) void transpose_v_k(
    const __hip_bfloat16* __restrict__ vbf, __hip_bfloat16* __restrict__ vtb)
{
  __shared__ __hip_bfloat16 tile[64][72];
  const int s0 = blockIdx.x * 64, d0 = blockIdx.y * 64, bh = blockIdx.z;
  const int tid = threadIdx.x;
  const int rr = tid >> 3;
  const int cc8 = (tid & 7) * 8;
  #pragma unroll
  for (int it = 0; it < 2; ++it) {
    const int r = rr + it * 32;
    *(bf16x8v*)&tile[r][cc8] =
        *(const bf16x8v*)&vbf[((size_t)bh * S_ + s0 + r) * DH_ + d0 + cc8];
  }
  __syncthreads();
  #pragma unroll
  for (int it = 0; it < 2; ++it) {
    const int r = rr + it * 32;
    bf16x8v tmp;
    #pragma unroll
    for (int e = 0; e < 8; ++e) tmp[e] = *(__bf16*)&tile[cc8 + e][r];
    *(bf16x8v*)&vtb[((size_t)bh * DH_ + d0 + r) * S_ + s0 + cc8] = tmp;
  }
}

// ---------------- per-(b,h) scans ------------------------------------------
__global__ __launch_bounds__(64) void gate_scan_k(
    const float* __restrict__ ig, const float* __restrict__ fg,
    float* __restrict__ lfc, float* __restrict__ aa, float* __restrict__ rm)
{
  const int bh = blockIdx.x;
  const int lane = threadIdx.x;
  const float* fgp = fg + bh * S_;
  const float* igp = ig + bh * S_;
  float v[16];
  float run = 0.f;
  #pragma unroll
  for (int i = 0; i < 16; ++i) {
    const float x = fgp[lane * 16 + i];
    const float lf = fminf(x, 0.f) - log1pf(expf(-fabsf(x)));
    run += lf;
    v[i] = run;
  }
  float inc = run;
  #pragma unroll
  for (int off = 1; off < 64; off <<= 1) {
    const float o = __shfl_up(inc, off);
    if (lane >= off) inc += o;
  }
  const float excl = inc - run;
  float rv[16];
  float rmx = -INFINITY;
  #pragma unroll
  for (int i = 0; i < 16; ++i) {
    const float l = v[i] + excl;
    lfc[bh * S_ + lane * 16 + i] = l;
    const float a = igp[lane * 16 + i] - l;
    aa[bh * S_ + lane * 16 + i] = a;
    rmx = fmaxf(rmx, a);
    rv[i] = rmx;
  }
  float incm = rmx;
  #pragma unroll
  for (int off = 1; off < 64; off <<= 1) {
    const float o = __shfl_up(incm, off);
    if (lane >= off) incm = fmaxf(incm, o);
  }
  float exm = __shfl_up(incm, 1);
  if (lane == 0) exm = -INFINITY;
  #pragma unroll
  for (int i = 0; i < 16; ++i) {
    rm[bh * S_ + lane * 16 + i] = fmaxf(rv[i], exm);
  }
}

// ---------------- mLSTM attention: partial kernel --------------------------
__global__ __launch_bounds__(256) void mlstm_part_k(
    const __hip_bfloat16* __restrict__ qbf, const __hip_bfloat16* __restrict__ kbf,
    const __hip_bfloat16* __restrict__ vtb,
    const float* __restrict__ aa, const float* __restrict__ rm,
    float* __restrict__ pacc, float* __restrict__ rsp)
{
  __shared__ __hip_bfloat16 Kl[2][6144];
  __shared__ __hip_bfloat16 Vl[2][6144];
  __shared__ __hip_bfloat16 Pl[4][16][40];
  const int bh = blockIdx.y;
  const int slot = blockIdx.x;
  int t = 0, base = 0;
  #pragma unroll
  for (int s = 0; s < 16; ++s) {
    const int sz = (s >> 2) + 1;
    if (slot >= base + sz) { base += sz; t = s + 1; }
  }
  const int c = slot - base;
  const int jt_lo = c * 8;
  const int jt_hi = min(jt_lo + 8, 2 * t + 2);

  const int wave = threadIdx.x >> 6, lane = threadIdx.x & 63;
  const int lrow = lane & 15, lgrp = lane >> 4;
  const int q0 = t * 64 + wave * 16;
  const __hip_bfloat16* Q  = qbf + (size_t)bh * S_ * DH_;
  const __hip_bfloat16* Kp = kbf + (size_t)bh * S_ * DH_;
  const __hip_bfloat16* VT = vtb + (size_t)bh * DH_ * S_;
  const float* aap = aa + bh * S_;
  const float* rmp = rm + bh * S_;

  bf16x8v qf[6];
  #pragma unroll
  for (int kk = 0; kk < 6; ++kk)
    qf[kk] = *(const bf16x8v*)&Q[(size_t)(q0 + lrow) * DH_ + kk * 32 + lgrp * 8];
  float rmi[4];
  #pragma unroll
  for (int r = 0; r < 4; ++r) rmi[r] = rmp[q0 + lgrp * 4 + r];

  const f32x4 zero4 = {0.f, 0.f, 0.f, 0.f};
  f32x4 hacc[12];
  #pragma unroll
  for (int dd = 0; dd < 12; ++dd) hacc[dd] = zero4;
  float rs[4] = {0.f, 0.f, 0.f, 0.f};
  const float scale = 0.07216878364870323f;   // 1/sqrt(192)
  const int myqmax = q0 + 15;

  bf16x8v kreg[3], vreg[3];
  const int s0_ = wave * 192 + lane;

  auto stage_load = [&](int j0s) {
    #pragma unroll
    for (int i = 0; i < 3; ++i) {
      const int s = s0_ + i * 64;
      const int kk = s >> 7, jr = (s >> 2) & 31, g = s & 3;
      kreg[i] = *(const bf16x8v*)&Kp[(size_t)(j0s + jr) * DH_ + kk * 32 + g * 8];
      const int d = s >> 2;
      vreg[i] = *(const bf16x8v*)&VT[(size_t)d * S_ + j0s + g * 8];
    }
  };
  auto stage_write = [&](int buf) {
    #pragma unroll
    for (int i = 0; i < 3; ++i) {
      const int s = s0_ + i * 64;
      *(bf16x8v*)&Kl[buf][s << 3] = kreg[i];
      *(bf16x8v*)&Vl[buf][s << 3] = vreg[i];
    }
  };

  stage_load(jt_lo * 32);
  stage_write(0);
  __syncthreads();
  int cur = 0;

  for (int jt = jt_lo; jt < jt_hi; ++jt) {
    const int j0 = jt * 32;
    const bool nxt = (jt + 1 < jt_hi);
    if (nxt) stage_load((jt + 1) * 32);
    if (j0 <= myqmax) {
      f32x4 sacc[2];
      sacc[0] = zero4; sacc[1] = zero4;
      #pragma unroll
      for (int jj = 0; jj < 2; ++jj) {
        #pragma unroll
        for (int kk = 0; kk < 6; ++kk) {
          const bf16x8v kf = *(const bf16x8v*)
              &Kl[cur][(kk * 128 + (jj * 16 + lrow) * 4 + lgrp) << 3];
          sacc[jj] = mfma16(qf[kk], kf, sacc[jj]);
        }
      }
      #pragma unroll
      for (int jj = 0; jj < 2; ++jj) {
        const int j = j0 + jj * 16 + lrow;
        const float ajv = aap[j];
        #pragma unroll
        for (int r = 0; r < 4; ++r) {
          const int i_ = q0 + lgrp * 4 + r;
          float cval = 0.f;
          if (j <= i_) cval = sacc[jj][r] * scale * __expf(ajv - rmi[r]);
          rs[r] += cval;
          Pl[wave][lgrp * 4 + r][jj * 16 + lrow] = __float2bfloat16(cval);
        }
      }
      const bf16x8v pf = *(const bf16x8v*)&Pl[wave][lrow][lgrp * 8];
      #pragma unroll
      for (int dd = 0; dd < 12; ++dd) {
        const bf16x8v vf = *(const bf16x8v*)
            &Vl[cur][(dd * 64 + lrow * 4 + lgrp) << 3];
        hacc[dd] = mfma16(pf, vf, hacc[dd]);
      }
    }
    if (nxt) stage_write(cur ^ 1);
    __syncthreads();
    cur ^= 1;
  }

  #pragma unroll
  for (int r = 0; r < 4; ++r) {
    #pragma unroll
    for (int m = 1; m < 16; m <<= 1) rs[r] += __shfl_xor(rs[r], m);
  }
  const size_t pb16 = ((size_t)bh * SLOTS_ + slot) * 16 + wave * 4 + lgrp;
  #pragma unroll
  for (int dd = 0; dd < 12; ++dd) {
    *(f32x4*)&pacc[(pb16 * 12 + dd) * 64 + lrow * 4] = hacc[dd];
  }
  if (lrow == 0) {
    #pragma unroll
    for (int r = 0; r < 4; ++r)
      rsp[((size_t)bh * SLOTS_ + slot) * 64 + wave * 16 + lgrp * 4 + r] = rs[r];
  }
}

// ---------------- mLSTM reduce + fused epilogue (bf16 h_state out) ---------
__global__ __launch_bounds__(256) void mlstm_red_k(
    const float* __restrict__ pacc, const float* __restrict__ rsp,
    const float* __restrict__ lfc, const float* __restrict__ rm,
    const float* __restrict__ ca, const float* __restrict__ xi,
    const float* __restrict__ nw, const float* __restrict__ nb,
    const float* __restrict__ skip, __hip_bfloat16* __restrict__ hs)
{
  const int t = blockIdx.x, bh = blockIdx.y;
  const int b = bh >> 2, hm = bh & 3;
  int base = 0;
  #pragma unroll
  for (int s = 0; s < 16; ++s) if (s < t) base += (s >> 2) + 1;
  const int nc = (t >> 2) + 1;

  const int wave = threadIdx.x >> 6, lane = threadIdx.x & 63;
  const int lrow = lane & 15, lgrp = lane >> 4;
  const int q0 = t * 64 + wave * 16;
  const float* lfcp = lfc + bh * S_;
  const float* rmp  = rm + bh * S_;

  f32x4 hsum[12];
  #pragma unroll
  for (int dd = 0; dd < 12; ++dd) hsum[dd] = f32x4{0.f, 0.f, 0.f, 0.f};
  float rst[4] = {0.f, 0.f, 0.f, 0.f};

  for (int cc = 0; cc < nc; ++cc) {
    const size_t pb16 = ((size_t)bh * SLOTS_ + base + cc) * 16 + wave * 4 + lgrp;
    #pragma unroll
    for (int dd = 0; dd < 12; ++dd) {
      const f32x4 p = *(const f32x4*)&pacc[(pb16 * 12 + dd) * 64 + lrow * 4];
      hsum[dd] += p;
    }
    #pragma unroll
    for (int r = 0; r < 4; ++r)
      rst[r] += rsp[((size_t)bh * SLOTS_ + base + cc) * 64 + wave * 16 + lgrp * 4 + r];
  }

  #pragma unroll
  for (int r = 0; r < 4; ++r) {
    const int i_ = q0 + lgrp * 4 + r;
    const int tok = b * S_ + i_;
    const float mld = lfcp[i_] + rmp[i_];
    const float nrm = fmaxf(fabsf(rst[r]), __expf(-mld)) + 1e-6f;
    float hv[12];
    float sum = 0.f, sq = 0.f;
    #pragma unroll
    for (int dd = 0; dd < 12; ++dd) {
      const float x = hsum[dd][r] / nrm;
      hv[dd] = x; sum += x; sq += x * x;
    }
    #pragma unroll
    for (int m = 1; m < 16; m <<= 1) {
      sum += __shfl_xor(sum, m);
      sq  += __shfl_xor(sq, m);
    }
    const float mean = sum * (1.f / 192.f);
    const float var  = sq * (1.f / 192.f) - mean * mean;
    const float rstd = rsqrtf(var + 1e-5f);
    #pragma unroll
    for (int dd = 0; dd < 12; ++dd) {
      const int cidx = hm * DH_ + dd * 16 + lrow;
      const float hn = (hv[dd] - mean) * rstd * nw[cidx] + nb[cidx];
      const float cav = ca[(size_t)tok * INNER_ + cidx];
      const float zz  = xi[(size_t)tok * 1536 + 768 + cidx];
      const float hsv = (hn + skip[cidx] * cav) * (zz / (1.f + __expf(-zz)));
      hs[(size_t)tok * INNER_ + cidx] = __float2bfloat16(hsv);
    }
  }
}

// ---------------------------------------------------------------------------
extern "C" void kernel_launch(void* const* d_in, const int* in_sizes, int n_in,
                              void* d_out, int out_size, void* d_ws, size_t ws_size,
                              hipStream_t stream) {
  const float* x      = (const float*)d_in[0];
  const float* W_up   = (const float*)d_in[1];
  const float* b_up   = (const float*)d_in[2];
  const float* Wq     = (const float*)d_in[3];
  const float* bq     = (const float*)d_in[4];
  const float* Wk     = (const float*)d_in[5];
  const float* bk     = (const float*)d_in[6];
  const float* Wv     = (const float*)d_in[7];
  const float* bv     = (const float*)d_in[8];
  const float* conv_w = (const float*)d_in[9];
  const float* conv_b = (const float*)d_in[10];
  const float* W_ig   = (const float*)d_in[11];
  const float* b_ig   = (const float*)d_in[12];
  const float* W_fg   = (const float*)d_in[13];
  const float* b_fg   = (const float*)d_in[14];
  const float* norm_w = (const float*)d_in[15];
  const float* norm_b = (const float*)d_in[16];
  const float* skip   = (const float*)d_in[17];
  const float* W_down = (const float*)d_in[18];
  const float* b_down = (const float*)d_in[19];
  float* out = (float*)d_out;

  char* ws = (char*)d_ws;
  constexpr size_t OFF_XI  = 0;
  constexpr size_t OFF_CA  = OFF_XI + (size_t)NTOK * 1536 * 4;
  constexpr size_t OFF_QBF = OFF_CA + (size_t)NTOK * INNER_ * 4;
  constexpr size_t OFF_KBF = OFF_QBF + (size_t)16 * S_ * DH_ * 2;
  constexpr size_t OFF_VBF = OFF_KBF + (size_t)16 * S_ * DH_ * 2;
  constexpr size_t OFF_IG  = OFF_VBF + (size_t)16 * S_ * DH_ * 2;
  constexpr size_t OFF_FG  = OFF_IG + (size_t)16 * S_ * 4;
  constexpr size_t OFF_LFC = OFF_FG + (size_t)16 * S_ * 4;
  constexpr size_t OFF_AA  = OFF_LFC + (size_t)16 * S_ * 4;
  constexpr size_t OFF_RM  = OFF_AA + (size_t)16 * S_ * 4;
  constexpr size_t OFF_HS  = OFF_RM + (size_t)16 * S_ * 4;
  constexpr size_t OFF_XB  = OFF_HS + (size_t)NTOK * INNER_ * 4;
  constexpr size_t OFF_WUB = OFF_XB + (size_t)NTOK * DIM_ * 2;
  constexpr size_t OFF_PAC = OFF_WUB + (size_t)1536 * DIM_ * 2;
  constexpr size_t OFF_RSP = OFF_PAC + (size_t)16 * SLOTS_ * 64 * 192 * 4;
  constexpr size_t OFF_WDB = OFF_RSP + (size_t)16 * SLOTS_ * 64 * 4;
  constexpr size_t OFF_VTB = OFF_WDB + (size_t)DIM_ * INNER_ * 2;

  float* x_inner = (float*)(ws + OFF_XI);
  float* conv_a  = (float*)(ws + OFF_CA);
  __hip_bfloat16* qbf = (__hip_bfloat16*)(ws + OFF_QBF);
  __hip_bfloat16* kbf = (__hip_bfloat16*)(ws + OFF_KBF);
  __hip_bfloat16* vbf = (__hip_bfloat16*)(ws + OFF_VBF);
  float* ig  = (float*)(ws + OFF_IG);
  float* fg  = (float*)(ws + OFF_FG);
  float* lfc = (float*)(ws + OFF_LFC);
  float* aav = (float*)(ws + OFF_AA);
  float* rmv = (float*)(ws + OFF_RM);
  __hip_bfloat16* hsb = (__hip_bfloat16*)(ws + OFF_HS);
  __hip_bfloat16* xb  = (__hip_bfloat16*)(ws + OFF_XB);
  __hip_bfloat16* wub = (__hip_bfloat16*)(ws + OFF_WUB);
  float* pacc = (float*)(ws + OFF_PAC);
  float* rsp  = (float*)(ws + OFF_RSP);
  __hip_bfloat16* wdb = (__hip_bfloat16*)(ws + OFF_WDB);
  __hip_bfloat16* vtb = (__hip_bfloat16*)(ws + OFF_VTB);
  float* pws = pacc;   // split-K partials alias dead pacc region

  // 0) casts
  cast_bf16_k<<<(NTOK * DIM_ / 4 + 255) / 256, 256, 0, stream>>>(x, xb, NTOK * DIM_ / 4);
  cast_bf16_k<<<(1536 * DIM_ / 4 + 255) / 256, 256, 0, stream>>>(W_up, wub, 1536 * DIM_ / 4);
  cast_bf16_k<<<(DIM_ * INNER_ / 4 + 255) / 256, 256, 0, stream>>>(W_down, wdb, DIM_ * INNER_ / 4);
  // 1) up-projection (LDS-staged bf16 MFMA)
  gemm_lds_k<DIM_, true><<<dim3(24, 64, 1), 256, 0, stream>>>(
      xb, DIM_, wub, DIM_, b_up, x_inner, 1536);
  // 2) depthwise conv + SiLU
  conv_silu_k<<<(NTOK * 192) / 256, 256, 0, stream>>>(x_inner, conv_w, conv_b, conv_a);
  // 3) headwise q,k,v + gates
  headwise_gates_k<<<NTOK, 256, 0, stream>>>(
      x_inner, conv_a, Wq, bq, Wk, bk, Wv, bv, W_ig, b_ig, W_fg, b_fg,
      qbf, kbf, vbf, ig, fg);
  // 3b) V transpose
  transpose_v_k<<<dim3(16, 3, 16), 256, 0, stream>>>(vbf, vtb);
  // 4) gate scans
  gate_scan_k<<<16, 64, 0, stream>>>(ig, fg, lfc, aav, rmv);
  // 5a) attention partials
  mlstm_part_k<<<dim3(SLOTS_, 16), 256, 0, stream>>>(qbf, kbf, vtb, aav, rmv, pacc, rsp);
  // 5b) reduce + epilogue
  mlstm_red_k<<<dim3(16, 16), 256, 0, stream>>>(
      pacc, rsp, lfc, rmv, conv_a, x_inner, norm_w, norm_b, skip, hsb);
  // 6) down-projection: LDS-staged split-K partials + reduce
  gemm_lds_k<192, false><<<dim3(6, 64, 4), 256, 0, stream>>>(
      hsb, INNER_, wdb, INNER_, nullptr, pws, DIM_);
  gemm_down_red_k<<<(NTOK * DIM_ / 4 + 255) / 256, 256, 0, stream>>>(pws, b_down, out);
}

// Round 11
// 128.743 us; speedup vs baseline: 1.4832x; 1.0860x over previous
//
#include <hip/hip_runtime.h>
#include <hip/hip_bf16.h>

// ---------------------------------------------------------------------------
// ViLLayer forward, round 10 (consolidation):
//   - conv_silu fused into headwise_gates (conv -> LDS -> qkv/gates); conv_a
//     still written once for the epilogue skip path.
//   - 3 cast kernels merged into one grid-strided kernel.
//   - down-proj split-K 4 -> 2 (KD=384/z), reduce reads 2 planes.
// ---------------------------------------------------------------------------

#define B_     4
#define S_     1024
#define DIM_   384
#define INNER_ 768
#define NHM_   4
#define DH_    192
#define NTOK   (B_*S_)      // 4096
#define SLOTS_ 40           // sum over t of ceil((t+1)/4)

typedef __attribute__((ext_vector_type(8))) __bf16 bf16x8v;
typedef __attribute__((ext_vector_type(4))) float  f32x4;

static __device__ __forceinline__ f32x4 mfma16(bf16x8v a, bf16x8v b, f32x4 c) {
  return __builtin_amdgcn_mfma_f32_16x16x32_bf16(a, b, c, 0, 0, 0);
}

// ---------------- fused cast fp32 -> bf16 for x, W_up, W_down --------------
__global__ __launch_bounds__(256) void cast_all_k(
    const float* __restrict__ x, const float* __restrict__ wup,
    const float* __restrict__ wdn,
    __hip_bfloat16* __restrict__ xb, __hip_bfloat16* __restrict__ wub,
    __hip_bfloat16* __restrict__ wdb)
{
  constexpr int N1 = NTOK * DIM_ / 4;
  constexpr int N2 = N1 + 1536 * DIM_ / 4;
  constexpr int N3 = N2 + DIM_ * INNER_ / 4;
  const int i = blockIdx.x * 256 + threadIdx.x;
  if (i >= N3) return;
  const float* src; __hip_bfloat16* dst; int j;
  if (i < N1)      { src = x;   dst = xb;  j = i; }
  else if (i < N2) { src = wup; dst = wub; j = i - N1; }
  else             { src = wdn; dst = wdb; j = i - N2; }
  const float4 v = *(const float4*)&src[(size_t)j * 4];
  dst[j * 4 + 0] = __float2bfloat16(v.x);
  dst[j * 4 + 1] = __float2bfloat16(v.y);
  dst[j * 4 + 2] = __float2bfloat16(v.z);
  dst[j * 4 + 3] = __float2bfloat16(v.w);
}

// ---------------- LDS-staged bf16 MFMA GEMM tile ---------------------------
template<int KD, bool BIAS>
__global__ __launch_bounds__(256) void gemm_lds_k(
    const __hip_bfloat16* __restrict__ A, int lda,
    const __hip_bfloat16* __restrict__ Bw, int ldb,
    const float* __restrict__ bias, float* __restrict__ C, int ldc)
{
  constexpr int NSTEP = KD / 64;
  __shared__ __hip_bfloat16 Al[2][4096];
  __shared__ __hip_bfloat16 Bl[2][4096];
  const int n0 = blockIdx.x * 64, m0 = blockIdx.y * 64;
  const int kofs = blockIdx.z * KD;
  const int tid = threadIdx.x;
  const int wave = tid >> 6, lane = tid & 63;
  const int lrow = lane & 15, lgrp = lane >> 4;

  const __hip_bfloat16* Ap = A + kofs;
  const __hip_bfloat16* Bp = Bw + kofs;
  float* Cp = C + (size_t)blockIdx.z * NTOK * ldc;

  const int r0 = tid >> 2, g0 = tid & 3;
  bf16x8v areg[2], breg[2];
  auto sload = [&](int k0) {
    areg[0] = *(const bf16x8v*)&Ap[(size_t)(m0 + r0) * lda + k0 + g0 * 8];
    breg[0] = *(const bf16x8v*)&Bp[(size_t)(n0 + r0) * ldb + k0 + g0 * 8];
    areg[1] = *(const bf16x8v*)&Ap[(size_t)(m0 + r0) * lda + k0 + 32 + g0 * 8];
    breg[1] = *(const bf16x8v*)&Bp[(size_t)(n0 + r0) * ldb + k0 + 32 + g0 * 8];
  };
  auto swrite = [&](int buf) {
    *(bf16x8v*)&Al[buf][(size_t)tid * 8]         = areg[0];
    *(bf16x8v*)&Bl[buf][(size_t)tid * 8]         = breg[0];
    *(bf16x8v*)&Al[buf][(size_t)(tid + 256) * 8] = areg[1];
    *(bf16x8v*)&Bl[buf][(size_t)(tid + 256) * 8] = breg[1];
  };

  f32x4 acc[4];
  #pragma unroll
  for (int nt = 0; nt < 4; ++nt) acc[nt] = f32x4{0.f, 0.f, 0.f, 0.f};

  sload(0);
  swrite(0);
  __syncthreads();
  int cur = 0;

  for (int ks = 0; ks < NSTEP; ++ks) {
    const bool nxt = (ks + 1 < NSTEP);
    if (nxt) sload((ks + 1) * 64);
    #pragma unroll
    for (int kk = 0; kk < 2; ++kk) {
      const bf16x8v af = *(const bf16x8v*)
          &Al[cur][(size_t)(kk * 256 + (wave * 16 + lrow) * 4 + lgrp) * 8];
      #pragma unroll
      for (int nt = 0; nt < 4; ++nt) {
        const bf16x8v bf = *(const bf16x8v*)
            &Bl[cur][(size_t)(kk * 256 + (nt * 16 + lrow) * 4 + lgrp) * 8];
        acc[nt] = mfma16(af, bf, acc[nt]);
      }
    }
    if (nxt) swrite(cur ^ 1);
    __syncthreads();
    cur ^= 1;
  }

  #pragma unroll
  for (int nt = 0; nt < 4; ++nt) {
    const int n = n0 + nt * 16 + lrow;
    const float bv = BIAS ? bias[n] : 0.f;
    #pragma unroll
    for (int r = 0; r < 4; ++r) {
      const int m = m0 + wave * 16 + lgrp * 4 + r;
      Cp[(size_t)m * ldc + n] = acc[nt][r] + bv;
    }
  }
}

// ---------------- down-proj reduce: out = pws[0] + pws[1] + bias -----------
__global__ __launch_bounds__(256) void gemm_down_red_k(
    const float* __restrict__ pws, const float* __restrict__ bias,
    float* __restrict__ out)
{
  const int i = blockIdx.x * 256 + threadIdx.x;
  if (i >= NTOK * DIM_ / 4) return;
  const int n4 = (i % (DIM_ / 4)) * 4;
  const float4 bv = *(const float4*)&bias[n4];
  float4 s0 = *(const float4*)&pws[(size_t)i * 4];
  const float4 s1 = *(const float4*)&pws[(size_t)NTOK * DIM_ + (size_t)i * 4];
  s0.x += s1.x + bv.x;
  s0.y += s1.y + bv.y;
  s0.z += s1.z + bv.z;
  s0.w += s1.w + bv.w;
  *(float4*)&out[(size_t)i * 4] = s0;
}

// ---------------- fused depthwise conv + SiLU + headwise qkv + gates -------
// one block per token; phase A: conv into LDS (+global conv_a for epilogue),
// phase B: headwise 4x4 projections, phase C: gate dot products.
__global__ __launch_bounds__(256) void conv_headwise_k(
    const float* __restrict__ xi, const float* __restrict__ cw,
    const float* __restrict__ cb, float* __restrict__ conv_a,
    const float* __restrict__ Wq, const float* __restrict__ bq,
    const float* __restrict__ Wk, const float* __restrict__ bk,
    const float* __restrict__ Wv, const float* __restrict__ bv,
    const float* __restrict__ Wig, const float* __restrict__ big,
    const float* __restrict__ Wfg, const float* __restrict__ bfg,
    __hip_bfloat16* __restrict__ qbf, __hip_bfloat16* __restrict__ kbf,
    __hip_bfloat16* __restrict__ vbf,
    float* __restrict__ ig, float* __restrict__ fg)
{
  __shared__ float cas[INNER_], qs[INNER_], ks[INNER_], vs[INNER_];
  const int t = blockIdx.x;
  const int b = t >> 10, s = t & 1023;
  const int y = s >> 5, x = s & 31;
  const int tb = t - s;
  const int tid = threadIdx.x;

  // ---- phase A: depthwise 3x3 conv + bias + SiLU (192 threads x float4) ---
  if (tid < 192) {
    const int c4 = tid * 4;
    float4 acc = *(const float4*)&cb[c4];
    #pragma unroll
    for (int ky = -1; ky <= 1; ++ky) {
      const int yy = y + ky;
      if (yy < 0 || yy > 31) continue;
      #pragma unroll
      for (int kx = -1; kx <= 1; ++kx) {
        const int xx = x + kx;
        if (xx < 0 || xx > 31) continue;
        const float4 v = *(const float4*)&xi[(size_t)(tb + (yy << 5) + xx) * 1536 + c4];
        const float4 w = *(const float4*)&cw[((ky + 1) * 3 + (kx + 1)) * INNER_ + c4];
        acc.x += v.x * w.x; acc.y += v.y * w.y;
        acc.z += v.z * w.z; acc.w += v.w * w.w;
      }
    }
    float4 o;
    o.x = acc.x / (1.f + __expf(-acc.x));
    o.y = acc.y / (1.f + __expf(-acc.y));
    o.z = acc.z / (1.f + __expf(-acc.z));
    o.w = acc.w / (1.f + __expf(-acc.w));
    *(float4*)&cas[c4] = o;
    *(float4*)&conv_a[(size_t)t * INNER_ + c4] = o;   // for epilogue skip path
  }
  __syncthreads();

  // ---- phase B: headwise 4x4 projections ----------------------------------
  if (tid < 192) {
    const float4 cav4 = *(const float4*)&cas[tid * 4];
    const float4 xmv4 = *(const float4*)&xi[(size_t)t * 1536 + tid * 4];
    const float cav[4] = {cav4.x, cav4.y, cav4.z, cav4.w};
    const float xmv[4] = {xmv4.x, xmv4.y, xmv4.z, xmv4.w};
    __hip_bfloat16 tq[4], tk[4], tv[4];
    #pragma unroll
    for (int o = 0; o < 4; ++o) {
      const int cidx = tid * 4 + o;
      float q = bq[cidx], k = bk[cidx], v = bv[cidx];
      #pragma unroll
      for (int d = 0; d < 4; ++d) {
        q += cav[d] * Wq[tid * 16 + o * 4 + d];
        k += cav[d] * Wk[tid * 16 + o * 4 + d];
        v += xmv[d] * Wv[tid * 16 + o * 4 + d];
      }
      qs[cidx] = q; ks[cidx] = k; vs[cidx] = v;
      tq[o] = __float2bfloat16(q);
      tk[o] = __float2bfloat16(k);
      tv[o] = __float2bfloat16(v);
    }
    const int cidx0 = tid * 4;
    const int hm = cidx0 / DH_, dd = cidx0 % DH_;
    const size_t o2 = ((size_t)(b * NHM_ + hm) * S_ + s) * DH_ + dd;
    *(uint2*)&qbf[o2] = *(uint2*)tq;
    *(uint2*)&kbf[o2] = *(uint2*)tk;
    *(uint2*)&vbf[o2] = *(uint2*)tv;
  }
  __syncthreads();

  // ---- phase C: gate pre-activations (8 groups x 32 lanes, float4) --------
  const int g = tid >> 5, l32 = tid & 31;
  const float* Wg = (g < 4) ? Wig : Wfg;
  const int h = g & 3;
  float sum = 0.f;
  #pragma unroll
  for (int i = 0; i < 6; ++i) {
    const int c4 = (l32 + i * 32) * 4;
    const float4 qv = *(const float4*)&qs[c4];
    const float4 kv = *(const float4*)&ks[c4];
    const float4 vv = *(const float4*)&vs[c4];
    const float4 wq = *(const float4*)&Wg[h * 2304 + c4];
    const float4 wk = *(const float4*)&Wg[h * 2304 + 768 + c4];
    const float4 wv = *(const float4*)&Wg[h * 2304 + 1536 + c4];
    sum += qv.x * wq.x + qv.y * wq.y + qv.z * wq.z + qv.w * wq.w;
    sum += kv.x * wk.x + kv.y * wk.y + kv.z * wk.z + kv.w * wk.w;
    sum += vv.x * wv.x + vv.y * wv.y + vv.z * wv.z + vv.w * wv.w;
  }
  #pragma unroll
  for (int m = 16; m >= 1; m >>= 1) sum += __shfl_xor(sum, m);
  if (l32 == 0) {
    if (g < 4) ig[(size_t)(b * NHM_ + h) * S_ + s] = sum + big[h];
    else       fg[(size_t)(b * NHM_ + h) * S_ + s] = sum + bfg[h];
  }
}

// ---------------- V transpose: vtb[bh][d][s] = vbf[bh][s][d] ---------------
__global__ __launch_bounds__(256) void transpose_v_k(
    const __hip_bfloat16* __restrict__ vbf, __hip_bfloat16* __restrict__ vtb)
{
  __shared__ __hip_bfloat16 tile[64][72];
  const int s0 = blockIdx.x * 64, d0 = blockIdx.y * 64, bh = blockIdx.z;
  const int tid = threadIdx.x;
  const int rr = tid >> 3;
  const int cc8 = (tid & 7) * 8;
  #pragma unroll
  for (int it = 0; it < 2; ++it) {
    const int r = rr + it * 32;
    *(bf16x8v*)&tile[r][cc8] =
        *(const bf16x8v*)&vbf[((size_t)bh * S_ + s0 + r) * DH_ + d0 + cc8];
  }
  __syncthreads();
  #pragma unroll
  for (int it = 0; it < 2; ++it) {
    const int r = rr + it * 32;
    bf16x8v tmp;
    #pragma unroll
    for (int e = 0; e < 8; ++e) tmp[e] = *(__bf16*)&tile[cc8 + e][r];
    *(bf16x8v*)&vtb[((size_t)bh * DH_ + d0 + r) * S_ + s0 + cc8] = tmp;
  }
}

// ---------------- per-(b,h) scans ------------------------------------------
__global__ __launch_bounds__(64) void gate_scan_k(
    const float* __restrict__ ig, const float* __restrict__ fg,
    float* __restrict__ lfc, float* __restrict__ aa, float* __restrict__ rm)
{
  const int bh = blockIdx.x;
  const int lane = threadIdx.x;
  const float* fgp = fg + bh * S_;
  const float* igp = ig + bh * S_;
  float v[16];
  float run = 0.f;
  #pragma unroll
  for (int i = 0; i < 16; ++i) {
    const float x = fgp[lane * 16 + i];
    const float lf = fminf(x, 0.f) - log1pf(expf(-fabsf(x)));
    run += lf;
    v[i] = run;
  }
  float inc = run;
  #pragma unroll
  for (int off = 1; off < 64; off <<= 1) {
    const float o = __shfl_up(inc, off);
    if (lane >= off) inc += o;
  }
  const float excl = inc - run;
  float rv[16];
  float rmx = -INFINITY;
  #pragma unroll
  for (int i = 0; i < 16; ++i) {
    const float l = v[i] + excl;
    lfc[bh * S_ + lane * 16 + i] = l;
    const float a = igp[lane * 16 + i] - l;
    aa[bh * S_ + lane * 16 + i] = a;
    rmx = fmaxf(rmx, a);
    rv[i] = rmx;
  }
  float incm = rmx;
  #pragma unroll
  for (int off = 1; off < 64; off <<= 1) {
    const float o = __shfl_up(incm, off);
    if (lane >= off) incm = fmaxf(incm, o);
  }
  float exm = __shfl_up(incm, 1);
  if (lane == 0) exm = -INFINITY;
  #pragma unroll
  for (int i = 0; i < 16; ++i) {
    rm[bh * S_ + lane * 16 + i] = fmaxf(rv[i], exm);
  }
}

// ---------------- mLSTM attention: partial kernel --------------------------
__global__ __launch_bounds__(256) void mlstm_part_k(
    const __hip_bfloat16* __restrict__ qbf, const __hip_bfloat16* __restrict__ kbf,
    const __hip_bfloat16* __restrict__ vtb,
    const float* __restrict__ aa, const float* __restrict__ rm,
    float* __restrict__ pacc, float* __restrict__ rsp)
{
  __shared__ __hip_bfloat16 Kl[2][6144];
  __shared__ __hip_bfloat16 Vl[2][6144];
  __shared__ __hip_bfloat16 Pl[4][16][40];
  const int bh = blockIdx.y;
  const int slot = blockIdx.x;
  int t = 0, base = 0;
  #pragma unroll
  for (int s = 0; s < 16; ++s) {
    const int sz = (s >> 2) + 1;
    if (slot >= base + sz) { base += sz; t = s + 1; }
  }
  const int c = slot - base;
  const int jt_lo = c * 8;
  const int jt_hi = min(jt_lo + 8, 2 * t + 2);

  const int wave = threadIdx.x >> 6, lane = threadIdx.x & 63;
  const int lrow = lane & 15, lgrp = lane >> 4;
  const int q0 = t * 64 + wave * 16;
  const __hip_bfloat16* Q  = qbf + (size_t)bh * S_ * DH_;
  const __hip_bfloat16* Kp = kbf + (size_t)bh * S_ * DH_;
  const __hip_bfloat16* VT = vtb + (size_t)bh * DH_ * S_;
  const float* aap = aa + bh * S_;
  const float* rmp = rm + bh * S_;

  bf16x8v qf[6];
  #pragma unroll
  for (int kk = 0; kk < 6; ++kk)
    qf[kk] = *(const bf16x8v*)&Q[(size_t)(q0 + lrow) * DH_ + kk * 32 + lgrp * 8];
  float rmi[4];
  #pragma unroll
  for (int r = 0; r < 4; ++r) rmi[r] = rmp[q0 + lgrp * 4 + r];

  const f32x4 zero4 = {0.f, 0.f, 0.f, 0.f};
  f32x4 hacc[12];
  #pragma unroll
  for (int dd = 0; dd < 12; ++dd) hacc[dd] = zero4;
  float rs[4] = {0.f, 0.f, 0.f, 0.f};
  const float scale = 0.07216878364870323f;   // 1/sqrt(192)
  const int myqmax = q0 + 15;

  bf16x8v kreg[3], vreg[3];
  const int s0_ = wave * 192 + lane;

  auto stage_load = [&](int j0s) {
    #pragma unroll
    for (int i = 0; i < 3; ++i) {
      const int s = s0_ + i * 64;
      const int kk = s >> 7, jr = (s >> 2) & 31, g = s & 3;
      kreg[i] = *(const bf16x8v*)&Kp[(size_t)(j0s + jr) * DH_ + kk * 32 + g * 8];
      const int d = s >> 2;
      vreg[i] = *(const bf16x8v*)&VT[(size_t)d * S_ + j0s + g * 8];
    }
  };
  auto stage_write = [&](int buf) {
    #pragma unroll
    for (int i = 0; i < 3; ++i) {
      const int s = s0_ + i * 64;
      *(bf16x8v*)&Kl[buf][s << 3] = kreg[i];
      *(bf16x8v*)&Vl[buf][s << 3] = vreg[i];
    }
  };

  stage_load(jt_lo * 32);
  stage_write(0);
  __syncthreads();
  int cur = 0;

  for (int jt = jt_lo; jt < jt_hi; ++jt) {
    const int j0 = jt * 32;
    const bool nxt = (jt + 1 < jt_hi);
    if (nxt) stage_load((jt + 1) * 32);
    if (j0 <= myqmax) {
      f32x4 sacc[2];
      sacc[0] = zero4; sacc[1] = zero4;
      #pragma unroll
      for (int jj = 0; jj < 2; ++jj) {
        #pragma unroll
        for (int kk = 0; kk < 6; ++kk) {
          const bf16x8v kf = *(const bf16x8v*)
              &Kl[cur][(kk * 128 + (jj * 16 + lrow) * 4 + lgrp) << 3];
          sacc[jj] = mfma16(qf[kk], kf, sacc[jj]);
        }
      }
      #pragma unroll
      for (int jj = 0; jj < 2; ++jj) {
        const int j = j0 + jj * 16 + lrow;
        const float ajv = aap[j];
        #pragma unroll
        for (int r = 0; r < 4; ++r) {
          const int i_ = q0 + lgrp * 4 + r;
          float cval = 0.f;
          if (j <= i_) cval = sacc[jj][r] * scale * __expf(ajv - rmi[r]);
          rs[r] += cval;
          Pl[wave][lgrp * 4 + r][jj * 16 + lrow] = __float2bfloat16(cval);
        }
      }
      const bf16x8v pf = *(const bf16x8v*)&Pl[wave][lrow][lgrp * 8];
      #pragma unroll
      for (int dd = 0; dd < 12; ++dd) {
        const bf16x8v vf = *(const bf16x8v*)
            &Vl[cur][(dd * 64 + lrow * 4 + lgrp) << 3];
        hacc[dd] = mfma16(pf, vf, hacc[dd]);
      }
    }
    if (nxt) stage_write(cur ^ 1);
    __syncthreads();
    cur ^= 1;
  }

  #pragma unroll
  for (int r = 0; r < 4; ++r) {
    #pragma unroll
    for (int m = 1; m < 16; m <<= 1) rs[r] += __shfl_xor(rs[r], m);
  }
  const size_t pb16 = ((size_t)bh * SLOTS_ + slot) * 16 + wave * 4 + lgrp;
  #pragma unroll
  for (int dd = 0; dd < 12; ++dd) {
    *(f32x4*)&pacc[(pb16 * 12 + dd) * 64 + lrow * 4] = hacc[dd];
  }
  if (lrow == 0) {
    #pragma unroll
    for (int r = 0; r < 4; ++r)
      rsp[((size_t)bh * SLOTS_ + slot) * 64 + wave * 16 + lgrp * 4 + r] = rs[r];
  }
}

// ---------------- mLSTM reduce + fused epilogue (bf16 h_state out) ---------
__global__ __launch_bounds__(256) void mlstm_red_k(
    const float* __restrict__ pacc, const float* __restrict__ rsp,
    const float* __restrict__ lfc, const float* __restrict__ rm,
    const float* __restrict__ ca, const float* __restrict__ xi,
    const float* __restrict__ nw, const float* __restrict__ nb,
    const float* __restrict__ skip, __hip_bfloat16* __restrict__ hs)
{
  const int t = blockIdx.x, bh = blockIdx.y;
  const int b = bh >> 2, hm = bh & 3;
  int base = 0;
  #pragma unroll
  for (int s = 0; s < 16; ++s) if (s < t) base += (s >> 2) + 1;
  const int nc = (t >> 2) + 1;

  const int wave = threadIdx.x >> 6, lane = threadIdx.x & 63;
  const int lrow = lane & 15, lgrp = lane >> 4;
  const int q0 = t * 64 + wave * 16;
  const float* lfcp = lfc + bh * S_;
  const float* rmp  = rm + bh * S_;

  f32x4 hsum[12];
  #pragma unroll
  for (int dd = 0; dd < 12; ++dd) hsum[dd] = f32x4{0.f, 0.f, 0.f, 0.f};
  float rst[4] = {0.f, 0.f, 0.f, 0.f};

  for (int cc = 0; cc < nc; ++cc) {
    const size_t pb16 = ((size_t)bh * SLOTS_ + base + cc) * 16 + wave * 4 + lgrp;
    #pragma unroll
    for (int dd = 0; dd < 12; ++dd) {
      const f32x4 p = *(const f32x4*)&pacc[(pb16 * 12 + dd) * 64 + lrow * 4];
      hsum[dd] += p;
    }
    #pragma unroll
    for (int r = 0; r < 4; ++r)
      rst[r] += rsp[((size_t)bh * SLOTS_ + base + cc) * 64 + wave * 16 + lgrp * 4 + r];
  }

  #pragma unroll
  for (int r = 0; r < 4; ++r) {
    const int i_ = q0 + lgrp * 4 + r;
    const int tok = b * S_ + i_;
    const float mld = lfcp[i_] + rmp[i_];
    const float nrm = fmaxf(fabsf(rst[r]), __expf(-mld)) + 1e-6f;
    float hv[12];
    float sum = 0.f, sq = 0.f;
    #pragma unroll
    for (int dd = 0; dd < 12; ++dd) {
      const float x = hsum[dd][r] / nrm;
      hv[dd] = x; sum += x; sq += x * x;
    }
    #pragma unroll
    for (int m = 1; m < 16; m <<= 1) {
      sum += __shfl_xor(sum, m);
      sq  += __shfl_xor(sq, m);
    }
    const float mean = sum * (1.f / 192.f);
    const float var  = sq * (1.f / 192.f) - mean * mean;
    const float rstd = rsqrtf(var + 1e-5f);
    #pragma unroll
    for (int dd = 0; dd < 12; ++dd) {
      const int cidx = hm * DH_ + dd * 16 + lrow;
      const float hn = (hv[dd] - mean) * rstd * nw[cidx] + nb[cidx];
      const float cav = ca[(size_t)tok * INNER_ + cidx];
      const float zz  = xi[(size_t)tok * 1536 + 768 + cidx];
      const float hsv = (hn + skip[cidx] * cav) * (zz / (1.f + __expf(-zz)));
      hs[(size_t)tok * INNER_ + cidx] = __float2bfloat16(hsv);
    }
  }
}

// ---------------------------------------------------------------------------
extern "C" void kernel_launch(void* const* d_in, const int* in_sizes, int n_in,
                              void* d_out, int out_size, void* d_ws, size_t ws_size,
                              hipStream_t stream) {
  const float* x      = (const float*)d_in[0];
  const float* W_up   = (const float*)d_in[1];
  const float* b_up   = (const float*)d_in[2];
  const float* Wq     = (const float*)d_in[3];
  const float* bq     = (const float*)d_in[4];
  const float* Wk     = (const float*)d_in[5];
  const float* bk     = (const float*)d_in[6];
  const float* Wv     = (const float*)d_in[7];
  const float* bv     = (const float*)d_in[8];
  const float* conv_w = (const float*)d_in[9];
  const float* conv_b = (const float*)d_in[10];
  const float* W_ig   = (const float*)d_in[11];
  const float* b_ig   = (const float*)d_in[12];
  const float* W_fg   = (const float*)d_in[13];
  const float* b_fg   = (const float*)d_in[14];
  const float* norm_w = (const float*)d_in[15];
  const float* norm_b = (const float*)d_in[16];
  const float* skip   = (const float*)d_in[17];
  const float* W_down = (const float*)d_in[18];
  const float* b_down = (const float*)d_in[19];
  float* out = (float*)d_out;

  char* ws = (char*)d_ws;
  constexpr size_t OFF_XI  = 0;
  constexpr size_t OFF_CA  = OFF_XI + (size_t)NTOK * 1536 * 4;
  constexpr size_t OFF_QBF = OFF_CA + (size_t)NTOK * INNER_ * 4;
  constexpr size_t OFF_KBF = OFF_QBF + (size_t)16 * S_ * DH_ * 2;
  constexpr size_t OFF_VBF = OFF_KBF + (size_t)16 * S_ * DH_ * 2;
  constexpr size_t OFF_IG  = OFF_VBF + (size_t)16 * S_ * DH_ * 2;
  constexpr size_t OFF_FG  = OFF_IG + (size_t)16 * S_ * 4;
  constexpr size_t OFF_LFC = OFF_FG + (size_t)16 * S_ * 4;
  constexpr size_t OFF_AA  = OFF_LFC + (size_t)16 * S_ * 4;
  constexpr size_t OFF_RM  = OFF_AA + (size_t)16 * S_ * 4;
  constexpr size_t OFF_HS  = OFF_RM + (size_t)16 * S_ * 4;
  constexpr size_t OFF_XB  = OFF_HS + (size_t)NTOK * INNER_ * 4;
  constexpr size_t OFF_WUB = OFF_XB + (size_t)NTOK * DIM_ * 2;
  constexpr size_t OFF_PAC = OFF_WUB + (size_t)1536 * DIM_ * 2;
  constexpr size_t OFF_RSP = OFF_PAC + (size_t)16 * SLOTS_ * 64 * 192 * 4;
  constexpr size_t OFF_WDB = OFF_RSP + (size_t)16 * SLOTS_ * 64 * 4;
  constexpr size_t OFF_VTB = OFF_WDB + (size_t)DIM_ * INNER_ * 2;

  float* x_inner = (float*)(ws + OFF_XI);
  float* conv_a  = (float*)(ws + OFF_CA);
  __hip_bfloat16* qbf = (__hip_bfloat16*)(ws + OFF_QBF);
  __hip_bfloat16* kbf = (__hip_bfloat16*)(ws + OFF_KBF);
  __hip_bfloat16* vbf = (__hip_bfloat16*)(ws + OFF_VBF);
  float* ig  = (float*)(ws + OFF_IG);
  float* fg  = (float*)(ws + OFF_FG);
  float* lfc = (float*)(ws + OFF_LFC);
  float* aav = (float*)(ws + OFF_AA);
  float* rmv = (float*)(ws + OFF_RM);
  __hip_bfloat16* hsb = (__hip_bfloat16*)(ws + OFF_HS);
  __hip_bfloat16* xb  = (__hip_bfloat16*)(ws + OFF_XB);
  __hip_bfloat16* wub = (__hip_bfloat16*)(ws + OFF_WUB);
  float* pacc = (float*)(ws + OFF_PAC);
  float* rsp  = (float*)(ws + OFF_RSP);
  __hip_bfloat16* wdb = (__hip_bfloat16*)(ws + OFF_WDB);
  __hip_bfloat16* vtb = (__hip_bfloat16*)(ws + OFF_VTB);
  float* pws = pacc;   // split-K partials alias dead pacc region (12.6 MB)

  // 0) fused casts (x, W_up, W_down)
  {
    constexpr int N3 = NTOK * DIM_ / 4 + 1536 * DIM_ / 4 + DIM_ * INNER_ / 4;
    cast_all_k<<<(N3 + 255) / 256, 256, 0, stream>>>(x, W_up, W_down, xb, wub, wdb);
  }
  // 1) up-projection (LDS-staged bf16 MFMA)
  gemm_lds_k<DIM_, true><<<dim3(24, 64, 1), 256, 0, stream>>>(
      xb, DIM_, wub, DIM_, b_up, x_inner, 1536);
  // 2+3) fused depthwise conv + SiLU + headwise qkv + gates
  conv_headwise_k<<<NTOK, 256, 0, stream>>>(
      x_inner, conv_w, conv_b, conv_a,
      Wq, bq, Wk, bk, Wv, bv, W_ig, b_ig, W_fg, b_fg,
      qbf, kbf, vbf, ig, fg);
  // 3b) V transpose
  transpose_v_k<<<dim3(16, 3, 16), 256, 0, stream>>>(vbf, vtb);
  // 4) gate scans
  gate_scan_k<<<16, 64, 0, stream>>>(ig, fg, lfc, aav, rmv);
  // 5a) attention partials
  mlstm_part_k<<<dim3(SLOTS_, 16), 256, 0, stream>>>(qbf, kbf, vtb, aav, rmv, pacc, rsp);
  // 5b) reduce + epilogue
  mlstm_red_k<<<dim3(16, 16), 256, 0, stream>>>(
      pacc, rsp, lfc, rmv, conv_a, x_inner, norm_w, norm_b, skip, hsb);
  // 6) down-projection: LDS-staged split-K(2) partials + reduce
  gemm_lds_k<DIM_, false><<<dim3(6, 64, 2), 256, 0, stream>>>(
      hsb, INNER_, wdb, INNER_, nullptr, pws, DIM_);
  gemm_down_red_k<<<(NTOK * DIM_ / 4 + 255) / 256, 256, 0, stream>>>(pws, b_down, out);
}

// Round 12
// 119.611 us; speedup vs baseline: 1.5964x; 1.0764x over previous
//
#include <hip/hip_runtime.h>
#include <hip/hip_bf16.h>

// ---------------------------------------------------------------------------
// ViLLayer forward, round 11 (traffic + locality):
//   - up-proj writes x_m fp32 (stride 768) + silu(z) as bf16 gz (z never
//     needed raw) -> -19 MB traffic.
//   - conv_a stored bf16 (only feeds epilogue skip path; qk path keeps fp32
//     LDS copy) -> -12.6 MB.
//   - mlstm_part grid (bh, slot): XCD%8 == bh%8 -> per-XCD L2 holds 2 heads.
//   - transpose_v + gate_scan merged into one dispatch.
// ---------------------------------------------------------------------------

#define B_     4
#define S_     1024
#define DIM_   384
#define INNER_ 768
#define NHM_   4
#define DH_    192
#define NTOK   (B_*S_)      // 4096
#define SLOTS_ 40           // sum over t of ceil((t+1)/4)

typedef __attribute__((ext_vector_type(8))) __bf16 bf16x8v;
typedef __attribute__((ext_vector_type(4))) float  f32x4;

static __device__ __forceinline__ f32x4 mfma16(bf16x8v a, bf16x8v b, f32x4 c) {
  return __builtin_amdgcn_mfma_f32_16x16x32_bf16(a, b, c, 0, 0, 0);
}

// ---------------- fused cast fp32 -> bf16 for x, W_up, W_down --------------
__global__ __launch_bounds__(256) void cast_all_k(
    const float* __restrict__ x, const float* __restrict__ wup,
    const float* __restrict__ wdn,
    __hip_bfloat16* __restrict__ xb, __hip_bfloat16* __restrict__ wub,
    __hip_bfloat16* __restrict__ wdb)
{
  constexpr int N1 = NTOK * DIM_ / 4;
  constexpr int N2 = N1 + 1536 * DIM_ / 4;
  constexpr int N3 = N2 + DIM_ * INNER_ / 4;
  const int i = blockIdx.x * 256 + threadIdx.x;
  if (i >= N3) return;
  const float* src; __hip_bfloat16* dst; int j;
  if (i < N1)      { src = x;   dst = xb;  j = i; }
  else if (i < N2) { src = wup; dst = wub; j = i - N1; }
  else             { src = wdn; dst = wdb; j = i - N2; }
  const float4 v = *(const float4*)&src[(size_t)j * 4];
  dst[j * 4 + 0] = __float2bfloat16(v.x);
  dst[j * 4 + 1] = __float2bfloat16(v.y);
  dst[j * 4 + 2] = __float2bfloat16(v.z);
  dst[j * 4 + 3] = __float2bfloat16(v.w);
}

// ---------------- up-proj: LDS-staged bf16 MFMA, split epilogue ------------
// n<768 -> x_m fp32 [m][768]; n>=768 -> gz[m][n-768] = bf16(silu(v)).
__global__ __launch_bounds__(256) void gemm_up_lds_k(
    const __hip_bfloat16* __restrict__ A,
    const __hip_bfloat16* __restrict__ Bw,
    const float* __restrict__ bias, float* __restrict__ xm,
    __hip_bfloat16* __restrict__ gz)
{
  constexpr int NSTEP = DIM_ / 64;
  __shared__ __hip_bfloat16 Al[2][4096];
  __shared__ __hip_bfloat16 Bl[2][4096];
  const int n0 = blockIdx.x * 64, m0 = blockIdx.y * 64;
  const int tid = threadIdx.x;
  const int wave = tid >> 6, lane = tid & 63;
  const int lrow = lane & 15, lgrp = lane >> 4;

  const int r0 = tid >> 2, g0 = tid & 3;
  bf16x8v areg[2], breg[2];
  auto sload = [&](int k0) {
    areg[0] = *(const bf16x8v*)&A[(size_t)(m0 + r0) * DIM_ + k0 + g0 * 8];
    breg[0] = *(const bf16x8v*)&Bw[(size_t)(n0 + r0) * DIM_ + k0 + g0 * 8];
    areg[1] = *(const bf16x8v*)&A[(size_t)(m0 + r0) * DIM_ + k0 + 32 + g0 * 8];
    breg[1] = *(const bf16x8v*)&Bw[(size_t)(n0 + r0) * DIM_ + k0 + 32 + g0 * 8];
  };
  auto swrite = [&](int buf) {
    *(bf16x8v*)&Al[buf][(size_t)tid * 8]         = areg[0];
    *(bf16x8v*)&Bl[buf][(size_t)tid * 8]         = breg[0];
    *(bf16x8v*)&Al[buf][(size_t)(tid + 256) * 8] = areg[1];
    *(bf16x8v*)&Bl[buf][(size_t)(tid + 256) * 8] = breg[1];
  };

  f32x4 acc[4];
  #pragma unroll
  for (int nt = 0; nt < 4; ++nt) acc[nt] = f32x4{0.f, 0.f, 0.f, 0.f};

  sload(0); swrite(0);
  __syncthreads();
  int cur = 0;
  for (int ks = 0; ks < NSTEP; ++ks) {
    const bool nxt = (ks + 1 < NSTEP);
    if (nxt) sload((ks + 1) * 64);
    #pragma unroll
    for (int kk = 0; kk < 2; ++kk) {
      const bf16x8v af = *(const bf16x8v*)
          &Al[cur][(size_t)(kk * 256 + (wave * 16 + lrow) * 4 + lgrp) * 8];
      #pragma unroll
      for (int nt = 0; nt < 4; ++nt) {
        const bf16x8v bf = *(const bf16x8v*)
            &Bl[cur][(size_t)(kk * 256 + (nt * 16 + lrow) * 4 + lgrp) * 8];
        acc[nt] = mfma16(af, bf, acc[nt]);
      }
    }
    if (nxt) swrite(cur ^ 1);
    __syncthreads();
    cur ^= 1;
  }

  const bool zside = (n0 >= INNER_);
  #pragma unroll
  for (int nt = 0; nt < 4; ++nt) {
    const int n = n0 + nt * 16 + lrow;
    const float bv = bias[n];
    #pragma unroll
    for (int r = 0; r < 4; ++r) {
      const int m = m0 + wave * 16 + lgrp * 4 + r;
      const float v = acc[nt][r] + bv;
      if (!zside) {
        xm[(size_t)m * INNER_ + n] = v;
      } else {
        gz[(size_t)m * INNER_ + (n - INNER_)] =
            __float2bfloat16(v / (1.f + __expf(-v)));
      }
    }
  }
}

// ---------------- LDS-staged bf16 MFMA GEMM tile (down-proj) ---------------
template<int KD>
__global__ __launch_bounds__(256) void gemm_lds_k(
    const __hip_bfloat16* __restrict__ A, int lda,
    const __hip_bfloat16* __restrict__ Bw, int ldb,
    float* __restrict__ C, int ldc)
{
  constexpr int NSTEP = KD / 64;
  __shared__ __hip_bfloat16 Al[2][4096];
  __shared__ __hip_bfloat16 Bl[2][4096];
  const int n0 = blockIdx.x * 64, m0 = blockIdx.y * 64;
  const int kofs = blockIdx.z * KD;
  const int tid = threadIdx.x;
  const int wave = tid >> 6, lane = tid & 63;
  const int lrow = lane & 15, lgrp = lane >> 4;

  const __hip_bfloat16* Ap = A + kofs;
  const __hip_bfloat16* Bp = Bw + kofs;
  float* Cp = C + (size_t)blockIdx.z * NTOK * ldc;

  const int r0 = tid >> 2, g0 = tid & 3;
  bf16x8v areg[2], breg[2];
  auto sload = [&](int k0) {
    areg[0] = *(const bf16x8v*)&Ap[(size_t)(m0 + r0) * lda + k0 + g0 * 8];
    breg[0] = *(const bf16x8v*)&Bp[(size_t)(n0 + r0) * ldb + k0 + g0 * 8];
    areg[1] = *(const bf16x8v*)&Ap[(size_t)(m0 + r0) * lda + k0 + 32 + g0 * 8];
    breg[1] = *(const bf16x8v*)&Bp[(size_t)(n0 + r0) * ldb + k0 + 32 + g0 * 8];
  };
  auto swrite = [&](int buf) {
    *(bf16x8v*)&Al[buf][(size_t)tid * 8]         = areg[0];
    *(bf16x8v*)&Bl[buf][(size_t)tid * 8]         = breg[0];
    *(bf16x8v*)&Al[buf][(size_t)(tid + 256) * 8] = areg[1];
    *(bf16x8v*)&Bl[buf][(size_t)(tid + 256) * 8] = breg[1];
  };

  f32x4 acc[4];
  #pragma unroll
  for (int nt = 0; nt < 4; ++nt) acc[nt] = f32x4{0.f, 0.f, 0.f, 0.f};

  sload(0); swrite(0);
  __syncthreads();
  int cur = 0;
  for (int ks = 0; ks < NSTEP; ++ks) {
    const bool nxt = (ks + 1 < NSTEP);
    if (nxt) sload((ks + 1) * 64);
    #pragma unroll
    for (int kk = 0; kk < 2; ++kk) {
      const bf16x8v af = *(const bf16x8v*)
          &Al[cur][(size_t)(kk * 256 + (wave * 16 + lrow) * 4 + lgrp) * 8];
      #pragma unroll
      for (int nt = 0; nt < 4; ++nt) {
        const bf16x8v bf = *(const bf16x8v*)
            &Bl[cur][(size_t)(kk * 256 + (nt * 16 + lrow) * 4 + lgrp) * 8];
        acc[nt] = mfma16(af, bf, acc[nt]);
      }
    }
    if (nxt) swrite(cur ^ 1);
    __syncthreads();
    cur ^= 1;
  }

  #pragma unroll
  for (int nt = 0; nt < 4; ++nt) {
    const int n = n0 + nt * 16 + lrow;
    #pragma unroll
    for (int r = 0; r < 4; ++r) {
      const int m = m0 + wave * 16 + lgrp * 4 + r;
      Cp[(size_t)m * ldc + n] = acc[nt][r];
    }
  }
}

// ---------------- down-proj reduce: out = pws[0] + pws[1] + bias -----------
__global__ __launch_bounds__(256) void gemm_down_red_k(
    const float* __restrict__ pws, const float* __restrict__ bias,
    float* __restrict__ out)
{
  const int i = blockIdx.x * 256 + threadIdx.x;
  if (i >= NTOK * DIM_ / 4) return;
  const int n4 = (i % (DIM_ / 4)) * 4;
  const float4 bv = *(const float4*)&bias[n4];
  float4 s0 = *(const float4*)&pws[(size_t)i * 4];
  const float4 s1 = *(const float4*)&pws[(size_t)NTOK * DIM_ + (size_t)i * 4];
  s0.x += s1.x + bv.x;
  s0.y += s1.y + bv.y;
  s0.z += s1.z + bv.z;
  s0.w += s1.w + bv.w;
  *(float4*)&out[(size_t)i * 4] = s0;
}

// ---------------- fused depthwise conv + SiLU + headwise qkv + gates -------
__global__ __launch_bounds__(256) void conv_headwise_k(
    const float* __restrict__ xm, const float* __restrict__ cw,
    const float* __restrict__ cb, __hip_bfloat16* __restrict__ cab,
    const float* __restrict__ Wq, const float* __restrict__ bq,
    const float* __restrict__ Wk, const float* __restrict__ bk,
    const float* __restrict__ Wv, const float* __restrict__ bv,
    const float* __restrict__ Wig, const float* __restrict__ big,
    const float* __restrict__ Wfg, const float* __restrict__ bfg,
    __hip_bfloat16* __restrict__ qbf, __hip_bfloat16* __restrict__ kbf,
    __hip_bfloat16* __restrict__ vbf,
    float* __restrict__ ig, float* __restrict__ fg)
{
  __shared__ float cas[INNER_], qs[INNER_], ks[INNER_], vs[INNER_];
  const int t = blockIdx.x;
  const int b = t >> 10, s = t & 1023;
  const int y = s >> 5, x = s & 31;
  const int tb = t - s;
  const int tid = threadIdx.x;

  // ---- phase A: depthwise 3x3 conv + bias + SiLU --------------------------
  if (tid < 192) {
    const int c4 = tid * 4;
    float4 acc = *(const float4*)&cb[c4];
    #pragma unroll
    for (int ky = -1; ky <= 1; ++ky) {
      const int yy = y + ky;
      if (yy < 0 || yy > 31) continue;
      #pragma unroll
      for (int kx = -1; kx <= 1; ++kx) {
        const int xx = x + kx;
        if (xx < 0 || xx > 31) continue;
        const float4 v = *(const float4*)&xm[(size_t)(tb + (yy << 5) + xx) * INNER_ + c4];
        const float4 w = *(const float4*)&cw[((ky + 1) * 3 + (kx + 1)) * INNER_ + c4];
        acc.x += v.x * w.x; acc.y += v.y * w.y;
        acc.z += v.z * w.z; acc.w += v.w * w.w;
      }
    }
    float4 o;
    o.x = acc.x / (1.f + __expf(-acc.x));
    o.y = acc.y / (1.f + __expf(-acc.y));
    o.z = acc.z / (1.f + __expf(-acc.z));
    o.w = acc.w / (1.f + __expf(-acc.w));
    *(float4*)&cas[c4] = o;
    __hip_bfloat16 tc[4] = {__float2bfloat16(o.x), __float2bfloat16(o.y),
                            __float2bfloat16(o.z), __float2bfloat16(o.w)};
    *(uint2*)&cab[(size_t)t * INNER_ + c4] = *(uint2*)tc;   // epilogue skip path
  }
  __syncthreads();

  // ---- phase B: headwise 4x4 projections ----------------------------------
  if (tid < 192) {
    const float4 cav4 = *(const float4*)&cas[tid * 4];
    const float4 xmv4 = *(const float4*)&xm[(size_t)t * INNER_ + tid * 4];
    const float cav[4] = {cav4.x, cav4.y, cav4.z, cav4.w};
    const float xmv[4] = {xmv4.x, xmv4.y, xmv4.z, xmv4.w};
    __hip_bfloat16 tq[4], tk[4], tv[4];
    #pragma unroll
    for (int o = 0; o < 4; ++o) {
      const int cidx = tid * 4 + o;
      float q = bq[cidx], k = bk[cidx], v = bv[cidx];
      #pragma unroll
      for (int d = 0; d < 4; ++d) {
        q += cav[d] * Wq[tid * 16 + o * 4 + d];
        k += cav[d] * Wk[tid * 16 + o * 4 + d];
        v += xmv[d] * Wv[tid * 16 + o * 4 + d];
      }
      qs[cidx] = q; ks[cidx] = k; vs[cidx] = v;
      tq[o] = __float2bfloat16(q);
      tk[o] = __float2bfloat16(k);
      tv[o] = __float2bfloat16(v);
    }
    const int cidx0 = tid * 4;
    const int hm = cidx0 / DH_, dd = cidx0 % DH_;
    const size_t o2 = ((size_t)(b * NHM_ + hm) * S_ + s) * DH_ + dd;
    *(uint2*)&qbf[o2] = *(uint2*)tq;
    *(uint2*)&kbf[o2] = *(uint2*)tk;
    *(uint2*)&vbf[o2] = *(uint2*)tv;
  }
  __syncthreads();

  // ---- phase C: gate pre-activations --------------------------------------
  const int g = tid >> 5, l32 = tid & 31;
  const float* Wg = (g < 4) ? Wig : Wfg;
  const int h = g & 3;
  float sum = 0.f;
  #pragma unroll
  for (int i = 0; i < 6; ++i) {
    const int c4 = (l32 + i * 32) * 4;
    const float4 qv = *(const float4*)&qs[c4];
    const float4 kv = *(const float4*)&ks[c4];
    const float4 vv = *(const float4*)&vs[c4];
    const float4 wq = *(const float4*)&Wg[h * 2304 + c4];
    const float4 wk = *(const float4*)&Wg[h * 2304 + 768 + c4];
    const float4 wv = *(const float4*)&Wg[h * 2304 + 1536 + c4];
    sum += qv.x * wq.x + qv.y * wq.y + qv.z * wq.z + qv.w * wq.w;
    sum += kv.x * wk.x + kv.y * wk.y + kv.z * wk.z + kv.w * wk.w;
    sum += vv.x * wv.x + vv.y * wv.y + vv.z * wv.z + vv.w * wv.w;
  }
  #pragma unroll
  for (int m = 16; m >= 1; m >>= 1) sum += __shfl_xor(sum, m);
  if (l32 == 0) {
    if (g < 4) ig[(size_t)(b * NHM_ + h) * S_ + s] = sum + big[h];
    else       fg[(size_t)(b * NHM_ + h) * S_ + s] = sum + bfg[h];
  }
}

// ---------------- merged: V transpose (blocks 0..767) + gate scans (768..783)
__global__ __launch_bounds__(256) void aux_k(
    const __hip_bfloat16* __restrict__ vbf, __hip_bfloat16* __restrict__ vtb,
    const float* __restrict__ ig, const float* __restrict__ fg,
    float* __restrict__ lfc, float* __restrict__ aa, float* __restrict__ rm)
{
  const int blk = blockIdx.x;
  if (blk < 768) {
    __shared__ __hip_bfloat16 tile[64][72];
    const int s0 = (blk & 15) * 64;
    const int d0 = ((blk >> 4) % 3) * 64;
    const int bh = blk / 48;
    const int tid = threadIdx.x;
    const int rr = tid >> 3;
    const int cc8 = (tid & 7) * 8;
    #pragma unroll
    for (int it = 0; it < 2; ++it) {
      const int r = rr + it * 32;
      *(bf16x8v*)&tile[r][cc8] =
          *(const bf16x8v*)&vbf[((size_t)bh * S_ + s0 + r) * DH_ + d0 + cc8];
    }
    __syncthreads();
    #pragma unroll
    for (int it = 0; it < 2; ++it) {
      const int r = rr + it * 32;
      bf16x8v tmp;
      #pragma unroll
      for (int e = 0; e < 8; ++e) tmp[e] = *(__bf16*)&tile[cc8 + e][r];
      *(bf16x8v*)&vtb[((size_t)bh * DH_ + d0 + r) * S_ + s0 + cc8] = tmp;
    }
    return;
  }
  // gate-scan role
  if (threadIdx.x >= 64) return;
  const int bh = blk - 768;
  const int lane = threadIdx.x;
  const float* fgp = fg + bh * S_;
  const float* igp = ig + bh * S_;
  float v[16];
  float run = 0.f;
  #pragma unroll
  for (int i = 0; i < 16; ++i) {
    const float xv = fgp[lane * 16 + i];
    const float lf = fminf(xv, 0.f) - log1pf(expf(-fabsf(xv)));
    run += lf;
    v[i] = run;
  }
  float inc = run;
  #pragma unroll
  for (int off = 1; off < 64; off <<= 1) {
    const float o = __shfl_up(inc, off);
    if (lane >= off) inc += o;
  }
  const float excl = inc - run;
  float rv[16];
  float rmx = -INFINITY;
  #pragma unroll
  for (int i = 0; i < 16; ++i) {
    const float l = v[i] + excl;
    lfc[bh * S_ + lane * 16 + i] = l;
    const float a = igp[lane * 16 + i] - l;
    aa[bh * S_ + lane * 16 + i] = a;
    rmx = fmaxf(rmx, a);
    rv[i] = rmx;
  }
  float incm = rmx;
  #pragma unroll
  for (int off = 1; off < 64; off <<= 1) {
    const float o = __shfl_up(incm, off);
    if (lane >= off) incm = fmaxf(incm, o);
  }
  float exm = __shfl_up(incm, 1);
  if (lane == 0) exm = -INFINITY;
  #pragma unroll
  for (int i = 0; i < 16; ++i) {
    rm[bh * S_ + lane * 16 + i] = fmaxf(rv[i], exm);
  }
}

// ---------------- mLSTM attention: partial kernel --------------------------
// grid (16 bh, SLOTS_): linear%8 == bh%8 -> per-XCD L2 holds 2 heads' K/V/Q.
__global__ __launch_bounds__(256) void mlstm_part_k(
    const __hip_bfloat16* __restrict__ qbf, const __hip_bfloat16* __restrict__ kbf,
    const __hip_bfloat16* __restrict__ vtb,
    const float* __restrict__ aa, const float* __restrict__ rm,
    float* __restrict__ pacc, float* __restrict__ rsp)
{
  __shared__ __hip_bfloat16 Kl[2][6144];
  __shared__ __hip_bfloat16 Vl[2][6144];
  __shared__ __hip_bfloat16 Pl[4][16][40];
  const int bh = blockIdx.x;
  const int slot = blockIdx.y;
  int t = 0, base = 0;
  #pragma unroll
  for (int s = 0; s < 16; ++s) {
    const int sz = (s >> 2) + 1;
    if (slot >= base + sz) { base += sz; t = s + 1; }
  }
  const int c = slot - base;
  const int jt_lo = c * 8;
  const int jt_hi = min(jt_lo + 8, 2 * t + 2);

  const int wave = threadIdx.x >> 6, lane = threadIdx.x & 63;
  const int lrow = lane & 15, lgrp = lane >> 4;
  const int q0 = t * 64 + wave * 16;
  const __hip_bfloat16* Q  = qbf + (size_t)bh * S_ * DH_;
  const __hip_bfloat16* Kp = kbf + (size_t)bh * S_ * DH_;
  const __hip_bfloat16* VT = vtb + (size_t)bh * DH_ * S_;
  const float* aap = aa + bh * S_;
  const float* rmp = rm + bh * S_;

  bf16x8v qf[6];
  #pragma unroll
  for (int kk = 0; kk < 6; ++kk)
    qf[kk] = *(const bf16x8v*)&Q[(size_t)(q0 + lrow) * DH_ + kk * 32 + lgrp * 8];
  float rmi[4];
  #pragma unroll
  for (int r = 0; r < 4; ++r) rmi[r] = rmp[q0 + lgrp * 4 + r];

  const f32x4 zero4 = {0.f, 0.f, 0.f, 0.f};
  f32x4 hacc[12];
  #pragma unroll
  for (int dd = 0; dd < 12; ++dd) hacc[dd] = zero4;
  float rs[4] = {0.f, 0.f, 0.f, 0.f};
  const float scale = 0.07216878364870323f;   // 1/sqrt(192)
  const int myqmax = q0 + 15;

  bf16x8v kreg[3], vreg[3];
  const int s0_ = wave * 192 + lane;

  auto stage_load = [&](int j0s) {
    #pragma unroll
    for (int i = 0; i < 3; ++i) {
      const int s = s0_ + i * 64;
      const int kk = s >> 7, jr = (s >> 2) & 31, g = s & 3;
      kreg[i] = *(const bf16x8v*)&Kp[(size_t)(j0s + jr) * DH_ + kk * 32 + g * 8];
      const int d = s >> 2;
      vreg[i] = *(const bf16x8v*)&VT[(size_t)d * S_ + j0s + g * 8];
    }
  };
  auto stage_write = [&](int buf) {
    #pragma unroll
    for (int i = 0; i < 3; ++i) {
      const int s = s0_ + i * 64;
      *(bf16x8v*)&Kl[buf][s << 3] = kreg[i];
      *(bf16x8v*)&Vl[buf][s << 3] = vreg[i];
    }
  };

  stage_load(jt_lo * 32);
  stage_write(0);
  __syncthreads();
  int cur = 0;

  for (int jt = jt_lo; jt < jt_hi; ++jt) {
    const int j0 = jt * 32;
    const bool nxt = (jt + 1 < jt_hi);
    if (nxt) stage_load((jt + 1) * 32);
    if (j0 <= myqmax) {
      f32x4 sacc[2];
      sacc[0] = zero4; sacc[1] = zero4;
      #pragma unroll
      for (int jj = 0; jj < 2; ++jj) {
        #pragma unroll
        for (int kk = 0; kk < 6; ++kk) {
          const bf16x8v kf = *(const bf16x8v*)
              &Kl[cur][(kk * 128 + (jj * 16 + lrow) * 4 + lgrp) << 3];
          sacc[jj] = mfma16(qf[kk], kf, sacc[jj]);
        }
      }
      #pragma unroll
      for (int jj = 0; jj < 2; ++jj) {
        const int j = j0 + jj * 16 + lrow;
        const float ajv = aap[j];
        #pragma unroll
        for (int r = 0; r < 4; ++r) {
          const int i_ = q0 + lgrp * 4 + r;
          float cval = 0.f;
          if (j <= i_) cval = sacc[jj][r] * scale * __expf(ajv - rmi[r]);
          rs[r] += cval;
          Pl[wave][lgrp * 4 + r][jj * 16 + lrow] = __float2bfloat16(cval);
        }
      }
      const bf16x8v pf = *(const bf16x8v*)&Pl[wave][lrow][lgrp * 8];
      #pragma unroll
      for (int dd = 0; dd < 12; ++dd) {
        const bf16x8v vf = *(const bf16x8v*)
            &Vl[cur][(dd * 64 + lrow * 4 + lgrp) << 3];
        hacc[dd] = mfma16(pf, vf, hacc[dd]);
      }
    }
    if (nxt) stage_write(cur ^ 1);
    __syncthreads();
    cur ^= 1;
  }

  #pragma unroll
  for (int r = 0; r < 4; ++r) {
    #pragma unroll
    for (int m = 1; m < 16; m <<= 1) rs[r] += __shfl_xor(rs[r], m);
  }
  const size_t pb16 = ((size_t)bh * SLOTS_ + slot) * 16 + wave * 4 + lgrp;
  #pragma unroll
  for (int dd = 0; dd < 12; ++dd) {
    *(f32x4*)&pacc[(pb16 * 12 + dd) * 64 + lrow * 4] = hacc[dd];
  }
  if (lrow == 0) {
    #pragma unroll
    for (int r = 0; r < 4; ++r)
      rsp[((size_t)bh * SLOTS_ + slot) * 64 + wave * 16 + lgrp * 4 + r] = rs[r];
  }
}

// ---------------- mLSTM reduce + fused epilogue (bf16 h_state out) ---------
__global__ __launch_bounds__(256) void mlstm_red_k(
    const float* __restrict__ pacc, const float* __restrict__ rsp,
    const float* __restrict__ lfc, const float* __restrict__ rm,
    const __hip_bfloat16* __restrict__ cab, const __hip_bfloat16* __restrict__ gz,
    const float* __restrict__ nw, const float* __restrict__ nb,
    const float* __restrict__ skip, __hip_bfloat16* __restrict__ hs)
{
  const int t = blockIdx.x, bh = blockIdx.y;
  const int b = bh >> 2, hm = bh & 3;
  int base = 0;
  #pragma unroll
  for (int s = 0; s < 16; ++s) if (s < t) base += (s >> 2) + 1;
  const int nc = (t >> 2) + 1;

  const int wave = threadIdx.x >> 6, lane = threadIdx.x & 63;
  const int lrow = lane & 15, lgrp = lane >> 4;
  const int q0 = t * 64 + wave * 16;
  const float* lfcp = lfc + bh * S_;
  const float* rmp  = rm + bh * S_;

  f32x4 hsum[12];
  #pragma unroll
  for (int dd = 0; dd < 12; ++dd) hsum[dd] = f32x4{0.f, 0.f, 0.f, 0.f};
  float rst[4] = {0.f, 0.f, 0.f, 0.f};

  for (int cc = 0; cc < nc; ++cc) {
    const size_t pb16 = ((size_t)bh * SLOTS_ + base + cc) * 16 + wave * 4 + lgrp;
    #pragma unroll
    for (int dd = 0; dd < 12; ++dd) {
      const f32x4 p = *(const f32x4*)&pacc[(pb16 * 12 + dd) * 64 + lrow * 4];
      hsum[dd] += p;
    }
    #pragma unroll
    for (int r = 0; r < 4; ++r)
      rst[r] += rsp[((size_t)bh * SLOTS_ + base + cc) * 64 + wave * 16 + lgrp * 4 + r];
  }

  #pragma unroll
  for (int r = 0; r < 4; ++r) {
    const int i_ = q0 + lgrp * 4 + r;
    const int tok = b * S_ + i_;
    const float mld = lfcp[i_] + rmp[i_];
    const float nrm = fmaxf(fabsf(rst[r]), __expf(-mld)) + 1e-6f;
    float hv[12];
    float sum = 0.f, sq = 0.f;
    #pragma unroll
    for (int dd = 0; dd < 12; ++dd) {
      const float x = hsum[dd][r] / nrm;
      hv[dd] = x; sum += x; sq += x * x;
    }
    #pragma unroll
    for (int m = 1; m < 16; m <<= 1) {
      sum += __shfl_xor(sum, m);
      sq  += __shfl_xor(sq, m);
    }
    const float mean = sum * (1.f / 192.f);
    const float var  = sq * (1.f / 192.f) - mean * mean;
    const float rstd = rsqrtf(var + 1e-5f);
    #pragma unroll
    for (int dd = 0; dd < 12; ++dd) {
      const int cidx = hm * DH_ + dd * 16 + lrow;
      const float hn = (hv[dd] - mean) * rstd * nw[cidx] + nb[cidx];
      const float cav = __bfloat162float(cab[(size_t)tok * INNER_ + cidx]);
      const float gzv = __bfloat162float(gz[(size_t)tok * INNER_ + cidx]);
      const float hsv = (hn + skip[cidx] * cav) * gzv;
      hs[(size_t)tok * INNER_ + cidx] = __float2bfloat16(hsv);
    }
  }
}

// ---------------------------------------------------------------------------
extern "C" void kernel_launch(void* const* d_in, const int* in_sizes, int n_in,
                              void* d_out, int out_size, void* d_ws, size_t ws_size,
                              hipStream_t stream) {
  const float* x      = (const float*)d_in[0];
  const float* W_up   = (const float*)d_in[1];
  const float* b_up   = (const float*)d_in[2];
  const float* Wq     = (const float*)d_in[3];
  const float* bq     = (const float*)d_in[4];
  const float* Wk     = (const float*)d_in[5];
  const float* bk     = (const float*)d_in[6];
  const float* Wv     = (const float*)d_in[7];
  const float* bv     = (const float*)d_in[8];
  const float* conv_w = (const float*)d_in[9];
  const float* conv_b = (const float*)d_in[10];
  const float* W_ig   = (const float*)d_in[11];
  const float* b_ig   = (const float*)d_in[12];
  const float* W_fg   = (const float*)d_in[13];
  const float* b_fg   = (const float*)d_in[14];
  const float* norm_w = (const float*)d_in[15];
  const float* norm_b = (const float*)d_in[16];
  const float* skip   = (const float*)d_in[17];
  const float* W_down = (const float*)d_in[18];
  const float* b_down = (const float*)d_in[19];
  float* out = (float*)d_out;

  char* ws = (char*)d_ws;
  constexpr size_t OFF_XM  = 0;                                     // 4096*768 f32
  constexpr size_t OFF_GZ  = OFF_XM + (size_t)NTOK * INNER_ * 4;    // bf16 silu(z)
  constexpr size_t OFF_CA  = OFF_GZ + (size_t)NTOK * INNER_ * 2;    // bf16 conv_act
  constexpr size_t OFF_QBF = OFF_CA + (size_t)NTOK * INNER_ * 2;
  constexpr size_t OFF_KBF = OFF_QBF + (size_t)16 * S_ * DH_ * 2;
  constexpr size_t OFF_VBF = OFF_KBF + (size_t)16 * S_ * DH_ * 2;
  constexpr size_t OFF_IG  = OFF_VBF + (size_t)16 * S_ * DH_ * 2;
  constexpr size_t OFF_FG  = OFF_IG + (size_t)16 * S_ * 4;
  constexpr size_t OFF_LFC = OFF_FG + (size_t)16 * S_ * 4;
  constexpr size_t OFF_AA  = OFF_LFC + (size_t)16 * S_ * 4;
  constexpr size_t OFF_RM  = OFF_AA + (size_t)16 * S_ * 4;
  constexpr size_t OFF_HS  = OFF_RM + (size_t)16 * S_ * 4;          // bf16 h_state
  constexpr size_t OFF_XB  = OFF_HS + (size_t)NTOK * INNER_ * 2;
  constexpr size_t OFF_WUB = OFF_XB + (size_t)NTOK * DIM_ * 2;
  constexpr size_t OFF_WDB = OFF_WUB + (size_t)1536 * DIM_ * 2;
  constexpr size_t OFF_VTB = OFF_WDB + (size_t)DIM_ * INNER_ * 2;
  constexpr size_t OFF_PAC = OFF_VTB + (size_t)16 * DH_ * S_ * 2;
  constexpr size_t OFF_RSP = OFF_PAC + (size_t)16 * SLOTS_ * 64 * 192 * 4;

  float* xm  = (float*)(ws + OFF_XM);
  __hip_bfloat16* gz  = (__hip_bfloat16*)(ws + OFF_GZ);
  __hip_bfloat16* cab = (__hip_bfloat16*)(ws + OFF_CA);
  __hip_bfloat16* qbf = (__hip_bfloat16*)(ws + OFF_QBF);
  __hip_bfloat16* kbf = (__hip_bfloat16*)(ws + OFF_KBF);
  __hip_bfloat16* vbf = (__hip_bfloat16*)(ws + OFF_VBF);
  float* ig  = (float*)(ws + OFF_IG);
  float* fg  = (float*)(ws + OFF_FG);
  float* lfc = (float*)(ws + OFF_LFC);
  float* aav = (float*)(ws + OFF_AA);
  float* rmv = (float*)(ws + OFF_RM);
  __hip_bfloat16* hsb = (__hip_bfloat16*)(ws + OFF_HS);
  __hip_bfloat16* xb  = (__hip_bfloat16*)(ws + OFF_XB);
  __hip_bfloat16* wub = (__hip_bfloat16*)(ws + OFF_WUB);
  __hip_bfloat16* wdb = (__hip_bfloat16*)(ws + OFF_WDB);
  __hip_bfloat16* vtb = (__hip_bfloat16*)(ws + OFF_VTB);
  float* pacc = (float*)(ws + OFF_PAC);
  float* rsp  = (float*)(ws + OFF_RSP);
  float* pws  = pacc;   // down-proj split-K partials alias dead pacc region

  // 0) fused casts (x, W_up, W_down)
  {
    constexpr int N3 = NTOK * DIM_ / 4 + 1536 * DIM_ / 4 + DIM_ * INNER_ / 4;
    cast_all_k<<<(N3 + 255) / 256, 256, 0, stream>>>(x, W_up, W_down, xb, wub, wdb);
  }
  // 1) up-projection: x_m fp32 + silu(z) bf16
  gemm_up_lds_k<<<dim3(24, 64), 256, 0, stream>>>(xb, wub, b_up, xm, gz);
  // 2+3) fused conv + SiLU + headwise qkv + gates
  conv_headwise_k<<<NTOK, 256, 0, stream>>>(
      xm, conv_w, conv_b, cab,
      Wq, bq, Wk, bk, Wv, bv, W_ig, b_ig, W_fg, b_fg,
      qbf, kbf, vbf, ig, fg);
  // 3b+4) merged V transpose + gate scans
  aux_k<<<784, 256, 0, stream>>>(vbf, vtb, ig, fg, lfc, aav, rmv);
  // 5a) attention partials (bh-major grid for XCD L2 locality)
  mlstm_part_k<<<dim3(16, SLOTS_), 256, 0, stream>>>(qbf, kbf, vtb, aav, rmv, pacc, rsp);
  // 5b) reduce + epilogue
  mlstm_red_k<<<dim3(16, 16), 256, 0, stream>>>(
      pacc, rsp, lfc, rmv, cab, gz, norm_w, norm_b, skip, hsb);
  // 6) down-projection: LDS-staged split-K(2) partials + reduce
  gemm_lds_k<DIM_><<<dim3(6, 64, 2), 256, 0, stream>>>(
      hsb, INNER_, wdb, INNER_, pws, DIM_);
  gemm_down_red_k<<<(NTOK * DIM_ / 4 + 255) / 256, 256, 0, stream>>>(pws, b_down, out);
}

// Round 13
// 112.144 us; speedup vs baseline: 1.7027x; 1.0666x over previous
//
#include <hip/hip_runtime.h>
#include <hip/hip_bf16.h>

// ---------------------------------------------------------------------------
// ViLLayer forward, round 12 (traffic):
//   - attention partials (pacc) stored bf16 (rowsums stay fp32): 63 -> 31 MB.
//   - down-proj single-pass (no split-K): LDS-staged KD=768, writes out
//     directly with bias; removes partial buffer + reduce dispatch.
// ---------------------------------------------------------------------------

#define B_     4
#define S_     1024
#define DIM_   384
#define INNER_ 768
#define NHM_   4
#define DH_    192
#define NTOK   (B_*S_)      // 4096
#define SLOTS_ 40           // sum over t of ceil((t+1)/4)

typedef __attribute__((ext_vector_type(8))) __bf16 bf16x8v;
typedef __attribute__((ext_vector_type(4))) float  f32x4;

static __device__ __forceinline__ f32x4 mfma16(bf16x8v a, bf16x8v b, f32x4 c) {
  return __builtin_amdgcn_mfma_f32_16x16x32_bf16(a, b, c, 0, 0, 0);
}

// ---------------- fused cast fp32 -> bf16 for x, W_up, W_down --------------
__global__ __launch_bounds__(256) void cast_all_k(
    const float* __restrict__ x, const float* __restrict__ wup,
    const float* __restrict__ wdn,
    __hip_bfloat16* __restrict__ xb, __hip_bfloat16* __restrict__ wub,
    __hip_bfloat16* __restrict__ wdb)
{
  constexpr int N1 = NTOK * DIM_ / 4;
  constexpr int N2 = N1 + 1536 * DIM_ / 4;
  constexpr int N3 = N2 + DIM_ * INNER_ / 4;
  const int i = blockIdx.x * 256 + threadIdx.x;
  if (i >= N3) return;
  const float* src; __hip_bfloat16* dst; int j;
  if (i < N1)      { src = x;   dst = xb;  j = i; }
  else if (i < N2) { src = wup; dst = wub; j = i - N1; }
  else             { src = wdn; dst = wdb; j = i - N2; }
  const float4 v = *(const float4*)&src[(size_t)j * 4];
  dst[j * 4 + 0] = __float2bfloat16(v.x);
  dst[j * 4 + 1] = __float2bfloat16(v.y);
  dst[j * 4 + 2] = __float2bfloat16(v.z);
  dst[j * 4 + 3] = __float2bfloat16(v.w);
}

// ---------------- up-proj: LDS-staged bf16 MFMA, split epilogue ------------
__global__ __launch_bounds__(256) void gemm_up_lds_k(
    const __hip_bfloat16* __restrict__ A,
    const __hip_bfloat16* __restrict__ Bw,
    const float* __restrict__ bias, float* __restrict__ xm,
    __hip_bfloat16* __restrict__ gz)
{
  constexpr int NSTEP = DIM_ / 64;
  __shared__ __hip_bfloat16 Al[2][4096];
  __shared__ __hip_bfloat16 Bl[2][4096];
  const int n0 = blockIdx.x * 64, m0 = blockIdx.y * 64;
  const int tid = threadIdx.x;
  const int wave = tid >> 6, lane = tid & 63;
  const int lrow = lane & 15, lgrp = lane >> 4;

  const int r0 = tid >> 2, g0 = tid & 3;
  bf16x8v areg[2], breg[2];
  auto sload = [&](int k0) {
    areg[0] = *(const bf16x8v*)&A[(size_t)(m0 + r0) * DIM_ + k0 + g0 * 8];
    breg[0] = *(const bf16x8v*)&Bw[(size_t)(n0 + r0) * DIM_ + k0 + g0 * 8];
    areg[1] = *(const bf16x8v*)&A[(size_t)(m0 + r0) * DIM_ + k0 + 32 + g0 * 8];
    breg[1] = *(const bf16x8v*)&Bw[(size_t)(n0 + r0) * DIM_ + k0 + 32 + g0 * 8];
  };
  auto swrite = [&](int buf) {
    *(bf16x8v*)&Al[buf][(size_t)tid * 8]         = areg[0];
    *(bf16x8v*)&Bl[buf][(size_t)tid * 8]         = breg[0];
    *(bf16x8v*)&Al[buf][(size_t)(tid + 256) * 8] = areg[1];
    *(bf16x8v*)&Bl[buf][(size_t)(tid + 256) * 8] = breg[1];
  };

  f32x4 acc[4];
  #pragma unroll
  for (int nt = 0; nt < 4; ++nt) acc[nt] = f32x4{0.f, 0.f, 0.f, 0.f};

  sload(0); swrite(0);
  __syncthreads();
  int cur = 0;
  for (int ks = 0; ks < NSTEP; ++ks) {
    const bool nxt = (ks + 1 < NSTEP);
    if (nxt) sload((ks + 1) * 64);
    #pragma unroll
    for (int kk = 0; kk < 2; ++kk) {
      const bf16x8v af = *(const bf16x8v*)
          &Al[cur][(size_t)(kk * 256 + (wave * 16 + lrow) * 4 + lgrp) * 8];
      #pragma unroll
      for (int nt = 0; nt < 4; ++nt) {
        const bf16x8v bf = *(const bf16x8v*)
            &Bl[cur][(size_t)(kk * 256 + (nt * 16 + lrow) * 4 + lgrp) * 8];
        acc[nt] = mfma16(af, bf, acc[nt]);
      }
    }
    if (nxt) swrite(cur ^ 1);
    __syncthreads();
    cur ^= 1;
  }

  const bool zside = (n0 >= INNER_);
  #pragma unroll
  for (int nt = 0; nt < 4; ++nt) {
    const int n = n0 + nt * 16 + lrow;
    const float bv = bias[n];
    #pragma unroll
    for (int r = 0; r < 4; ++r) {
      const int m = m0 + wave * 16 + lgrp * 4 + r;
      const float v = acc[nt][r] + bv;
      if (!zside) {
        xm[(size_t)m * INNER_ + n] = v;
      } else {
        gz[(size_t)m * INNER_ + (n - INNER_)] =
            __float2bfloat16(v / (1.f + __expf(-v)));
      }
    }
  }
}

// ---------------- LDS-staged bf16 MFMA GEMM (down-proj, single pass) -------
template<int KD>
__global__ __launch_bounds__(256) void gemm_lds_k(
    const __hip_bfloat16* __restrict__ A, int lda,
    const __hip_bfloat16* __restrict__ Bw, int ldb,
    const float* __restrict__ bias, float* __restrict__ C, int ldc)
{
  constexpr int NSTEP = KD / 64;
  __shared__ __hip_bfloat16 Al[2][4096];
  __shared__ __hip_bfloat16 Bl[2][4096];
  const int n0 = blockIdx.x * 64, m0 = blockIdx.y * 64;
  const int tid = threadIdx.x;
  const int wave = tid >> 6, lane = tid & 63;
  const int lrow = lane & 15, lgrp = lane >> 4;

  const int r0 = tid >> 2, g0 = tid & 3;
  bf16x8v areg[2], breg[2];
  auto sload = [&](int k0) {
    areg[0] = *(const bf16x8v*)&A[(size_t)(m0 + r0) * lda + k0 + g0 * 8];
    breg[0] = *(const bf16x8v*)&Bw[(size_t)(n0 + r0) * ldb + k0 + g0 * 8];
    areg[1] = *(const bf16x8v*)&A[(size_t)(m0 + r0) * lda + k0 + 32 + g0 * 8];
    breg[1] = *(const bf16x8v*)&Bw[(size_t)(n0 + r0) * ldb + k0 + 32 + g0 * 8];
  };
  auto swrite = [&](int buf) {
    *(bf16x8v*)&Al[buf][(size_t)tid * 8]         = areg[0];
    *(bf16x8v*)&Bl[buf][(size_t)tid * 8]         = breg[0];
    *(bf16x8v*)&Al[buf][(size_t)(tid + 256) * 8] = areg[1];
    *(bf16x8v*)&Bl[buf][(size_t)(tid + 256) * 8] = breg[1];
  };

  f32x4 acc[4];
  #pragma unroll
  for (int nt = 0; nt < 4; ++nt) acc[nt] = f32x4{0.f, 0.f, 0.f, 0.f};

  sload(0); swrite(0);
  __syncthreads();
  int cur = 0;
  for (int ks = 0; ks < NSTEP; ++ks) {
    const bool nxt = (ks + 1 < NSTEP);
    if (nxt) sload((ks + 1) * 64);
    #pragma unroll
    for (int kk = 0; kk < 2; ++kk) {
      const bf16x8v af = *(const bf16x8v*)
          &Al[cur][(size_t)(kk * 256 + (wave * 16 + lrow) * 4 + lgrp) * 8];
      #pragma unroll
      for (int nt = 0; nt < 4; ++nt) {
        const bf16x8v bf = *(const bf16x8v*)
            &Bl[cur][(size_t)(kk * 256 + (nt * 16 + lrow) * 4 + lgrp) * 8];
        acc[nt] = mfma16(af, bf, acc[nt]);
      }
    }
    if (nxt) swrite(cur ^ 1);
    __syncthreads();
    cur ^= 1;
  }

  #pragma unroll
  for (int nt = 0; nt < 4; ++nt) {
    const int n = n0 + nt * 16 + lrow;
    const float bv = bias[n];
    #pragma unroll
    for (int r = 0; r < 4; ++r) {
      const int m = m0 + wave * 16 + lgrp * 4 + r;
      C[(size_t)m * ldc + n] = acc[nt][r] + bv;
    }
  }
}

// ---------------- fused depthwise conv + SiLU + headwise qkv + gates -------
__global__ __launch_bounds__(256) void conv_headwise_k(
    const float* __restrict__ xm, const float* __restrict__ cw,
    const float* __restrict__ cb, __hip_bfloat16* __restrict__ cab,
    const float* __restrict__ Wq, const float* __restrict__ bq,
    const float* __restrict__ Wk, const float* __restrict__ bk,
    const float* __restrict__ Wv, const float* __restrict__ bv,
    const float* __restrict__ Wig, const float* __restrict__ big,
    const float* __restrict__ Wfg, const float* __restrict__ bfg,
    __hip_bfloat16* __restrict__ qbf, __hip_bfloat16* __restrict__ kbf,
    __hip_bfloat16* __restrict__ vbf,
    float* __restrict__ ig, float* __restrict__ fg)
{
  __shared__ float cas[INNER_], qs[INNER_], ks[INNER_], vs[INNER_];
  const int t = blockIdx.x;
  const int b = t >> 10, s = t & 1023;
  const int y = s >> 5, x = s & 31;
  const int tb = t - s;
  const int tid = threadIdx.x;

  if (tid < 192) {
    const int c4 = tid * 4;
    float4 acc = *(const float4*)&cb[c4];
    #pragma unroll
    for (int ky = -1; ky <= 1; ++ky) {
      const int yy = y + ky;
      if (yy < 0 || yy > 31) continue;
      #pragma unroll
      for (int kx = -1; kx <= 1; ++kx) {
        const int xx = x + kx;
        if (xx < 0 || xx > 31) continue;
        const float4 v = *(const float4*)&xm[(size_t)(tb + (yy << 5) + xx) * INNER_ + c4];
        const float4 w = *(const float4*)&cw[((ky + 1) * 3 + (kx + 1)) * INNER_ + c4];
        acc.x += v.x * w.x; acc.y += v.y * w.y;
        acc.z += v.z * w.z; acc.w += v.w * w.w;
      }
    }
    float4 o;
    o.x = acc.x / (1.f + __expf(-acc.x));
    o.y = acc.y / (1.f + __expf(-acc.y));
    o.z = acc.z / (1.f + __expf(-acc.z));
    o.w = acc.w / (1.f + __expf(-acc.w));
    *(float4*)&cas[c4] = o;
    __hip_bfloat16 tc[4] = {__float2bfloat16(o.x), __float2bfloat16(o.y),
                            __float2bfloat16(o.z), __float2bfloat16(o.w)};
    *(uint2*)&cab[(size_t)t * INNER_ + c4] = *(uint2*)tc;
  }
  __syncthreads();

  if (tid < 192) {
    const float4 cav4 = *(const float4*)&cas[tid * 4];
    const float4 xmv4 = *(const float4*)&xm[(size_t)t * INNER_ + tid * 4];
    const float cav[4] = {cav4.x, cav4.y, cav4.z, cav4.w};
    const float xmv[4] = {xmv4.x, xmv4.y, xmv4.z, xmv4.w};
    __hip_bfloat16 tq[4], tk[4], tv[4];
    #pragma unroll
    for (int o = 0; o < 4; ++o) {
      const int cidx = tid * 4 + o;
      float q = bq[cidx], k = bk[cidx], v = bv[cidx];
      #pragma unroll
      for (int d = 0; d < 4; ++d) {
        q += cav[d] * Wq[tid * 16 + o * 4 + d];
        k += cav[d] * Wk[tid * 16 + o * 4 + d];
        v += xmv[d] * Wv[tid * 16 + o * 4 + d];
      }
      qs[cidx] = q; ks[cidx] = k; vs[cidx] = v;
      tq[o] = __float2bfloat16(q);
      tk[o] = __float2bfloat16(k);
      tv[o] = __float2bfloat16(v);
    }
    const int cidx0 = tid * 4;
    const int hm = cidx0 / DH_, dd = cidx0 % DH_;
    const size_t o2 = ((size_t)(b * NHM_ + hm) * S_ + s) * DH_ + dd;
    *(uint2*)&qbf[o2] = *(uint2*)tq;
    *(uint2*)&kbf[o2] = *(uint2*)tk;
    *(uint2*)&vbf[o2] = *(uint2*)tv;
  }
  __syncthreads();

  const int g = tid >> 5, l32 = tid & 31;
  const float* Wg = (g < 4) ? Wig : Wfg;
  const int h = g & 3;
  float sum = 0.f;
  #pragma unroll
  for (int i = 0; i < 6; ++i) {
    const int c4 = (l32 + i * 32) * 4;
    const float4 qv = *(const float4*)&qs[c4];
    const float4 kv = *(const float4*)&ks[c4];
    const float4 vv = *(const float4*)&vs[c4];
    const float4 wq = *(const float4*)&Wg[h * 2304 + c4];
    const float4 wk = *(const float4*)&Wg[h * 2304 + 768 + c4];
    const float4 wv = *(const float4*)&Wg[h * 2304 + 1536 + c4];
    sum += qv.x * wq.x + qv.y * wq.y + qv.z * wq.z + qv.w * wq.w;
    sum += kv.x * wk.x + kv.y * wk.y + kv.z * wk.z + kv.w * wk.w;
    sum += vv.x * wv.x + vv.y * wv.y + vv.z * wv.z + vv.w * wv.w;
  }
  #pragma unroll
  for (int m = 16; m >= 1; m >>= 1) sum += __shfl_xor(sum, m);
  if (l32 == 0) {
    if (g < 4) ig[(size_t)(b * NHM_ + h) * S_ + s] = sum + big[h];
    else       fg[(size_t)(b * NHM_ + h) * S_ + s] = sum + bfg[h];
  }
}

// ---------------- merged: V transpose (blocks 0..767) + gate scans ---------
__global__ __launch_bounds__(256) void aux_k(
    const __hip_bfloat16* __restrict__ vbf, __hip_bfloat16* __restrict__ vtb,
    const float* __restrict__ ig, const float* __restrict__ fg,
    float* __restrict__ lfc, float* __restrict__ aa, float* __restrict__ rm)
{
  const int blk = blockIdx.x;
  if (blk < 768) {
    __shared__ __hip_bfloat16 tile[64][72];
    const int s0 = (blk & 15) * 64;
    const int d0 = ((blk >> 4) % 3) * 64;
    const int bh = blk / 48;
    const int tid = threadIdx.x;
    const int rr = tid >> 3;
    const int cc8 = (tid & 7) * 8;
    #pragma unroll
    for (int it = 0; it < 2; ++it) {
      const int r = rr + it * 32;
      *(bf16x8v*)&tile[r][cc8] =
          *(const bf16x8v*)&vbf[((size_t)bh * S_ + s0 + r) * DH_ + d0 + cc8];
    }
    __syncthreads();
    #pragma unroll
    for (int it = 0; it < 2; ++it) {
      const int r = rr + it * 32;
      bf16x8v tmp;
      #pragma unroll
      for (int e = 0; e < 8; ++e) tmp[e] = *(__bf16*)&tile[cc8 + e][r];
      *(bf16x8v*)&vtb[((size_t)bh * DH_ + d0 + r) * S_ + s0 + cc8] = tmp;
    }
    return;
  }
  if (threadIdx.x >= 64) return;
  const int bh = blk - 768;
  const int lane = threadIdx.x;
  const float* fgp = fg + bh * S_;
  const float* igp = ig + bh * S_;
  float v[16];
  float run = 0.f;
  #pragma unroll
  for (int i = 0; i < 16; ++i) {
    const float xv = fgp[lane * 16 + i];
    const float lf = fminf(xv, 0.f) - log1pf(expf(-fabsf(xv)));
    run += lf;
    v[i] = run;
  }
  float inc = run;
  #pragma unroll
  for (int off = 1; off < 64; off <<= 1) {
    const float o = __shfl_up(inc, off);
    if (lane >= off) inc += o;
  }
  const float excl = inc - run;
  float rv[16];
  float rmx = -INFINITY;
  #pragma unroll
  for (int i = 0; i < 16; ++i) {
    const float l = v[i] + excl;
    lfc[bh * S_ + lane * 16 + i] = l;
    const float a = igp[lane * 16 + i] - l;
    aa[bh * S_ + lane * 16 + i] = a;
    rmx = fmaxf(rmx, a);
    rv[i] = rmx;
  }
  float incm = rmx;
  #pragma unroll
  for (int off = 1; off < 64; off <<= 1) {
    const float o = __shfl_up(incm, off);
    if (lane >= off) incm = fmaxf(incm, o);
  }
  float exm = __shfl_up(incm, 1);
  if (lane == 0) exm = -INFINITY;
  #pragma unroll
  for (int i = 0; i < 16; ++i) {
    rm[bh * S_ + lane * 16 + i] = fmaxf(rv[i], exm);
  }
}

// ---------------- mLSTM attention: partial kernel (bf16 partials) ----------
__global__ __launch_bounds__(256) void mlstm_part_k(
    const __hip_bfloat16* __restrict__ qbf, const __hip_bfloat16* __restrict__ kbf,
    const __hip_bfloat16* __restrict__ vtb,
    const float* __restrict__ aa, const float* __restrict__ rm,
    __hip_bfloat16* __restrict__ pacc, float* __restrict__ rsp)
{
  __shared__ __hip_bfloat16 Kl[2][6144];
  __shared__ __hip_bfloat16 Vl[2][6144];
  __shared__ __hip_bfloat16 Pl[4][16][40];
  const int bh = blockIdx.x;
  const int slot = blockIdx.y;
  int t = 0, base = 0;
  #pragma unroll
  for (int s = 0; s < 16; ++s) {
    const int sz = (s >> 2) + 1;
    if (slot >= base + sz) { base += sz; t = s + 1; }
  }
  const int c = slot - base;
  const int jt_lo = c * 8;
  const int jt_hi = min(jt_lo + 8, 2 * t + 2);

  const int wave = threadIdx.x >> 6, lane = threadIdx.x & 63;
  const int lrow = lane & 15, lgrp = lane >> 4;
  const int q0 = t * 64 + wave * 16;
  const __hip_bfloat16* Q  = qbf + (size_t)bh * S_ * DH_;
  const __hip_bfloat16* Kp = kbf + (size_t)bh * S_ * DH_;
  const __hip_bfloat16* VT = vtb + (size_t)bh * DH_ * S_;
  const float* aap = aa + bh * S_;
  const float* rmp = rm + bh * S_;

  bf16x8v qf[6];
  #pragma unroll
  for (int kk = 0; kk < 6; ++kk)
    qf[kk] = *(const bf16x8v*)&Q[(size_t)(q0 + lrow) * DH_ + kk * 32 + lgrp * 8];
  float rmi[4];
  #pragma unroll
  for (int r = 0; r < 4; ++r) rmi[r] = rmp[q0 + lgrp * 4 + r];

  const f32x4 zero4 = {0.f, 0.f, 0.f, 0.f};
  f32x4 hacc[12];
  #pragma unroll
  for (int dd = 0; dd < 12; ++dd) hacc[dd] = zero4;
  float rs[4] = {0.f, 0.f, 0.f, 0.f};
  const float scale = 0.07216878364870323f;   // 1/sqrt(192)
  const int myqmax = q0 + 15;

  bf16x8v kreg[3], vreg[3];
  const int s0_ = wave * 192 + lane;

  auto stage_load = [&](int j0s) {
    #pragma unroll
    for (int i = 0; i < 3; ++i) {
      const int s = s0_ + i * 64;
      const int kk = s >> 7, jr = (s >> 2) & 31, g = s & 3;
      kreg[i] = *(const bf16x8v*)&Kp[(size_t)(j0s + jr) * DH_ + kk * 32 + g * 8];
      const int d = s >> 2;
      vreg[i] = *(const bf16x8v*)&VT[(size_t)d * S_ + j0s + g * 8];
    }
  };
  auto stage_write = [&](int buf) {
    #pragma unroll
    for (int i = 0; i < 3; ++i) {
      const int s = s0_ + i * 64;
      *(bf16x8v*)&Kl[buf][s << 3] = kreg[i];
      *(bf16x8v*)&Vl[buf][s << 3] = vreg[i];
    }
  };

  stage_load(jt_lo * 32);
  stage_write(0);
  __syncthreads();
  int cur = 0;

  for (int jt = jt_lo; jt < jt_hi; ++jt) {
    const int j0 = jt * 32;
    const bool nxt = (jt + 1 < jt_hi);
    if (nxt) stage_load((jt + 1) * 32);
    if (j0 <= myqmax) {
      f32x4 sacc[2];
      sacc[0] = zero4; sacc[1] = zero4;
      #pragma unroll
      for (int jj = 0; jj < 2; ++jj) {
        #pragma unroll
        for (int kk = 0; kk < 6; ++kk) {
          const bf16x8v kf = *(const bf16x8v*)
              &Kl[cur][(kk * 128 + (jj * 16 + lrow) * 4 + lgrp) << 3];
          sacc[jj] = mfma16(qf[kk], kf, sacc[jj]);
        }
      }
      #pragma unroll
      for (int jj = 0; jj < 2; ++jj) {
        const int j = j0 + jj * 16 + lrow;
        const float ajv = aap[j];
        #pragma unroll
        for (int r = 0; r < 4; ++r) {
          const int i_ = q0 + lgrp * 4 + r;
          float cval = 0.f;
          if (j <= i_) cval = sacc[jj][r] * scale * __expf(ajv - rmi[r]);
          rs[r] += cval;
          Pl[wave][lgrp * 4 + r][jj * 16 + lrow] = __float2bfloat16(cval);
        }
      }
      const bf16x8v pf = *(const bf16x8v*)&Pl[wave][lrow][lgrp * 8];
      #pragma unroll
      for (int dd = 0; dd < 12; ++dd) {
        const bf16x8v vf = *(const bf16x8v*)
            &Vl[cur][(dd * 64 + lrow * 4 + lgrp) << 3];
        hacc[dd] = mfma16(pf, vf, hacc[dd]);
      }
    }
    if (nxt) stage_write(cur ^ 1);
    __syncthreads();
    cur ^= 1;
  }

  #pragma unroll
  for (int r = 0; r < 4; ++r) {
    #pragma unroll
    for (int m = 1; m < 16; m <<= 1) rs[r] += __shfl_xor(rs[r], m);
  }
  const size_t pb16 = ((size_t)bh * SLOTS_ + slot) * 16 + wave * 4 + lgrp;
  #pragma unroll
  for (int dd = 0; dd < 12; ++dd) {
    __hip_bfloat16 tp[4] = {__float2bfloat16(hacc[dd][0]),
                            __float2bfloat16(hacc[dd][1]),
                            __float2bfloat16(hacc[dd][2]),
                            __float2bfloat16(hacc[dd][3])};
    *(uint2*)&pacc[(pb16 * 12 + dd) * 64 + lrow * 4] = *(uint2*)tp;
  }
  if (lrow == 0) {
    #pragma unroll
    for (int r = 0; r < 4; ++r)
      rsp[((size_t)bh * SLOTS_ + slot) * 64 + wave * 16 + lgrp * 4 + r] = rs[r];
  }
}

// ---------------- mLSTM reduce + fused epilogue (bf16 h_state out) ---------
__global__ __launch_bounds__(256) void mlstm_red_k(
    const __hip_bfloat16* __restrict__ pacc, const float* __restrict__ rsp,
    const float* __restrict__ lfc, const float* __restrict__ rm,
    const __hip_bfloat16* __restrict__ cab, const __hip_bfloat16* __restrict__ gz,
    const float* __restrict__ nw, const float* __restrict__ nb,
    const float* __restrict__ skip, __hip_bfloat16* __restrict__ hs)
{
  const int t = blockIdx.x, bh = blockIdx.y;
  const int b = bh >> 2, hm = bh & 3;
  int base = 0;
  #pragma unroll
  for (int s = 0; s < 16; ++s) if (s < t) base += (s >> 2) + 1;
  const int nc = (t >> 2) + 1;

  const int wave = threadIdx.x >> 6, lane = threadIdx.x & 63;
  const int lrow = lane & 15, lgrp = lane >> 4;
  const int q0 = t * 64 + wave * 16;
  const float* lfcp = lfc + bh * S_;
  const float* rmp  = rm + bh * S_;

  f32x4 hsum[12];
  #pragma unroll
  for (int dd = 0; dd < 12; ++dd) hsum[dd] = f32x4{0.f, 0.f, 0.f, 0.f};
  float rst[4] = {0.f, 0.f, 0.f, 0.f};

  for (int cc = 0; cc < nc; ++cc) {
    const size_t pb16 = ((size_t)bh * SLOTS_ + base + cc) * 16 + wave * 4 + lgrp;
    #pragma unroll
    for (int dd = 0; dd < 12; ++dd) {
      const uint2 pv = *(const uint2*)&pacc[(pb16 * 12 + dd) * 64 + lrow * 4];
      const __hip_bfloat16* pb = (const __hip_bfloat16*)&pv;
      hsum[dd][0] += __bfloat162float(pb[0]);
      hsum[dd][1] += __bfloat162float(pb[1]);
      hsum[dd][2] += __bfloat162float(pb[2]);
      hsum[dd][3] += __bfloat162float(pb[3]);
    }
    #pragma unroll
    for (int r = 0; r < 4; ++r)
      rst[r] += rsp[((size_t)bh * SLOTS_ + base + cc) * 64 + wave * 16 + lgrp * 4 + r];
  }

  #pragma unroll
  for (int r = 0; r < 4; ++r) {
    const int i_ = q0 + lgrp * 4 + r;
    const int tok = b * S_ + i_;
    const float mld = lfcp[i_] + rmp[i_];
    const float nrm = fmaxf(fabsf(rst[r]), __expf(-mld)) + 1e-6f;
    float hv[12];
    float sum = 0.f, sq = 0.f;
    #pragma unroll
    for (int dd = 0; dd < 12; ++dd) {
      const float x = hsum[dd][r] / nrm;
      hv[dd] = x; sum += x; sq += x * x;
    }
    #pragma unroll
    for (int m = 1; m < 16; m <<= 1) {
      sum += __shfl_xor(sum, m);
      sq  += __shfl_xor(sq, m);
    }
    const float mean = sum * (1.f / 192.f);
    const float var  = sq * (1.f / 192.f) - mean * mean;
    const float rstd = rsqrtf(var + 1e-5f);
    #pragma unroll
    for (int dd = 0; dd < 12; ++dd) {
      const int cidx = hm * DH_ + dd * 16 + lrow;
      const float hn = (hv[dd] - mean) * rstd * nw[cidx] + nb[cidx];
      const float cav = __bfloat162float(cab[(size_t)tok * INNER_ + cidx]);
      const float gzv = __bfloat162float(gz[(size_t)tok * INNER_ + cidx]);
      const float hsv = (hn + skip[cidx] * cav) * gzv;
      hs[(size_t)tok * INNER_ + cidx] = __float2bfloat16(hsv);
    }
  }
}

// ---------------------------------------------------------------------------
extern "C" void kernel_launch(void* const* d_in, const int* in_sizes, int n_in,
                              void* d_out, int out_size, void* d_ws, size_t ws_size,
                              hipStream_t stream) {
  const float* x      = (const float*)d_in[0];
  const float* W_up   = (const float*)d_in[1];
  const float* b_up   = (const float*)d_in[2];
  const float* Wq     = (const float*)d_in[3];
  const float* bq     = (const float*)d_in[4];
  const float* Wk     = (const float*)d_in[5];
  const float* bk     = (const float*)d_in[6];
  const float* Wv     = (const float*)d_in[7];
  const float* bv     = (const float*)d_in[8];
  const float* conv_w = (const float*)d_in[9];
  const float* conv_b = (const float*)d_in[10];
  const float* W_ig   = (const float*)d_in[11];
  const float* b_ig   = (const float*)d_in[12];
  const float* W_fg   = (const float*)d_in[13];
  const float* b_fg   = (const float*)d_in[14];
  const float* norm_w = (const float*)d_in[15];
  const float* norm_b = (const float*)d_in[16];
  const float* skip   = (const float*)d_in[17];
  const float* W_down = (const float*)d_in[18];
  const float* b_down = (const float*)d_in[19];
  float* out = (float*)d_out;

  char* ws = (char*)d_ws;
  constexpr size_t OFF_XM  = 0;                                     // 4096*768 f32
  constexpr size_t OFF_GZ  = OFF_XM + (size_t)NTOK * INNER_ * 4;    // bf16 silu(z)
  constexpr size_t OFF_CA  = OFF_GZ + (size_t)NTOK * INNER_ * 2;    // bf16 conv_act
  constexpr size_t OFF_QBF = OFF_CA + (size_t)NTOK * INNER_ * 2;
  constexpr size_t OFF_KBF = OFF_QBF + (size_t)16 * S_ * DH_ * 2;
  constexpr size_t OFF_VBF = OFF_KBF + (size_t)16 * S_ * DH_ * 2;
  constexpr size_t OFF_IG  = OFF_VBF + (size_t)16 * S_ * DH_ * 2;
  constexpr size_t OFF_FG  = OFF_IG + (size_t)16 * S_ * 4;
  constexpr size_t OFF_LFC = OFF_FG + (size_t)16 * S_ * 4;
  constexpr size_t OFF_AA  = OFF_LFC + (size_t)16 * S_ * 4;
  constexpr size_t OFF_RM  = OFF_AA + (size_t)16 * S_ * 4;
  constexpr size_t OFF_HS  = OFF_RM + (size_t)16 * S_ * 4;          // bf16 h_state
  constexpr size_t OFF_XB  = OFF_HS + (size_t)NTOK * INNER_ * 2;
  constexpr size_t OFF_WUB = OFF_XB + (size_t)NTOK * DIM_ * 2;
  constexpr size_t OFF_WDB = OFF_WUB + (size_t)1536 * DIM_ * 2;
  constexpr size_t OFF_VTB = OFF_WDB + (size_t)DIM_ * INNER_ * 2;
  constexpr size_t OFF_PAC = OFF_VTB + (size_t)16 * DH_ * S_ * 2;   // bf16 partials
  constexpr size_t OFF_RSP = OFF_PAC + (size_t)16 * SLOTS_ * 64 * 192 * 2;

  float* xm  = (float*)(ws + OFF_XM);
  __hip_bfloat16* gz  = (__hip_bfloat16*)(ws + OFF_GZ);
  __hip_bfloat16* cab = (__hip_bfloat16*)(ws + OFF_CA);
  __hip_bfloat16* qbf = (__hip_bfloat16*)(ws + OFF_QBF);
  __hip_bfloat16* kbf = (__hip_bfloat16*)(ws + OFF_KBF);
  __hip_bfloat16* vbf = (__hip_bfloat16*)(ws + OFF_VBF);
  float* ig  = (float*)(ws + OFF_IG);
  float* fg  = (float*)(ws + OFF_FG);
  float* lfc = (float*)(ws + OFF_LFC);
  float* aav = (float*)(ws + OFF_AA);
  float* rmv = (float*)(ws + OFF_RM);
  __hip_bfloat16* hsb = (__hip_bfloat16*)(ws + OFF_HS);
  __hip_bfloat16* xb  = (__hip_bfloat16*)(ws + OFF_XB);
  __hip_bfloat16* wub = (__hip_bfloat16*)(ws + OFF_WUB);
  __hip_bfloat16* wdb = (__hip_bfloat16*)(ws + OFF_WDB);
  __hip_bfloat16* vtb = (__hip_bfloat16*)(ws + OFF_VTB);
  __hip_bfloat16* pacc = (__hip_bfloat16*)(ws + OFF_PAC);
  float* rsp = (float*)(ws + OFF_RSP);

  // 0) fused casts (x, W_up, W_down)
  {
    constexpr int N3 = NTOK * DIM_ / 4 + 1536 * DIM_ / 4 + DIM_ * INNER_ / 4;
    cast_all_k<<<(N3 + 255) / 256, 256, 0, stream>>>(x, W_up, W_down, xb, wub, wdb);
  }
  // 1) up-projection: x_m fp32 + silu(z) bf16
  gemm_up_lds_k<<<dim3(24, 64), 256, 0, stream>>>(xb, wub, b_up, xm, gz);
  // 2+3) fused conv + SiLU + headwise qkv + gates
  conv_headwise_k<<<NTOK, 256, 0, stream>>>(
      xm, conv_w, conv_b, cab,
      Wq, bq, Wk, bk, Wv, bv, W_ig, b_ig, W_fg, b_fg,
      qbf, kbf, vbf, ig, fg);
  // 3b+4) merged V transpose + gate scans
  aux_k<<<784, 256, 0, stream>>>(vbf, vtb, ig, fg, lfc, aav, rmv);
  // 5a) attention partials (bf16 partials, bh-major grid for XCD L2 locality)
  mlstm_part_k<<<dim3(16, SLOTS_), 256, 0, stream>>>(qbf, kbf, vtb, aav, rmv, pacc, rsp);
  // 5b) reduce + epilogue
  mlstm_red_k<<<dim3(16, 16), 256, 0, stream>>>(
      pacc, rsp, lfc, rmv, cab, gz, norm_w, norm_b, skip, hsb);
  // 6) down-projection: single-pass LDS-staged bf16 MFMA, writes out + bias
  gemm_lds_k<INNER_><<<dim3(6, 64), 256, 0, stream>>>(
      hsb, INNER_, wdb, INNER_, b_down, out, DIM_);
}